// Round 1
// baseline (2964.126 us; speedup 1.0000x reference)
//
#include <hip/hip_runtime.h>
#include <hip/hip_bf16.h>
#include <cstdint>

#define DEV_INLINE __device__ __forceinline__

constexpr int NP  = 120000;   // points
constexpr int NB  = 8;        // batches
constexpr int NM  = 60000;    // centers
constexpr int KNN = 16;
constexpr int NE  = NM * KNN; // 960000 edges
constexpr float EPS = 1e-5f;

// output layout (flat f32)
constexpr size_t O_POS   = (size_t)NM * 128;
constexpr size_t O_BATCH = O_POS + (size_t)NM * 3;
constexpr size_t O_REFL  = O_BATCH + NM;
constexpr size_t O_SF    = O_REFL + NM;

// ---------------- device-global scratch (avoids ws_size assumptions) --------
__device__ float g_pos_s[(size_t)NP * 4];
__device__ float g_msg [(size_t)NE * 36];
__device__ float g_h1  [(size_t)NE * 64];
__device__ float g_pre2[(size_t)NE * 64];
__device__ float g_pre3[(size_t)NE * 128];
__device__ float g_agg [(size_t)NM * 128];
__device__ float g_bufA[(size_t)NM * 512];
__device__ float g_bufB[(size_t)NM * 512];
__device__ float g_obuf[(size_t)NM * 128];
__device__ float g_sum[512];
__device__ float g_sqs[512];
__device__ float g_cfa[512];
__device__ float g_cfb[512];

template<int ID> DEV_INLINE float* bufsel() {
  if constexpr (ID == 0) return g_msg;
  else if constexpr (ID == 1) return g_h1;
  else if constexpr (ID == 2) return g_pre2;
  else if constexpr (ID == 3) return g_pre3;
  else if constexpr (ID == 4) return g_agg;
  else if constexpr (ID == 5) return g_bufA;
  else if constexpr (ID == 6) return g_bufB;
  else return g_obuf;
}

// ---------------- small kernels ---------------------------------------------
__global__ void prep_pos(const float* __restrict__ pos, const int* __restrict__ batch,
                         const float* __restrict__ refl, const float* __restrict__ sf) {
  int i = blockIdx.x * blockDim.x + threadIdx.x;
  if (i >= NP) return;
  float s = sf[batch[i]];
  float4 v;
  v.x = pos[(size_t)i*3+0] / s;
  v.y = pos[(size_t)i*3+1] / s;
  v.z = pos[(size_t)i*3+2] / s;
  v.w = refl[i];             // gate == 1 exactly (size-1 softmax straight-through)
  *reinterpret_cast<float4*>(g_pos_s + (size_t)i*4) = v;
}

__global__ void tail_out(const float* __restrict__ pos, const int* __restrict__ batch,
                         const float* __restrict__ refl, const float* __restrict__ sf,
                         const int* __restrict__ idx, float* __restrict__ out) {
  int i = blockIdx.x * blockDim.x + threadIdx.x;
  if (i < NM) {
    int p = idx[i];
    out[O_POS + (size_t)i*3+0] = pos[(size_t)p*3+0];
    out[O_POS + (size_t)i*3+1] = pos[(size_t)p*3+1];
    out[O_POS + (size_t)i*3+2] = pos[(size_t)p*3+2];
    out[O_BATCH + i] = (float)batch[p];
    out[O_REFL  + i] = refl[p];
  }
  if (i < NB) out[O_SF + i] = sf[i];
}

__global__ void gather_msg(const float* __restrict__ x, const int* __restrict__ esrc,
                           const int* __restrict__ edst, const int* __restrict__ idx) {
  int e = blockIdx.x * blockDim.x + threadIdx.x;
  if (e >= NE) return;
  int s = esrc[e];
  int c = idx[edst[e]];
  const float4* xs = reinterpret_cast<const float4*>(x + (size_t)s * 32);
  float* mrow = g_msg + (size_t)e * 36;
#pragma unroll
  for (int q = 0; q < 8; q++)
    *reinterpret_cast<float4*>(mrow + q*4) = xs[q];
  float4 ps = *reinterpret_cast<const float4*>(g_pos_s + (size_t)s*4);
  float4 pc = *reinterpret_cast<const float4*>(g_pos_s + (size_t)c*4);
  mrow[32] = ps.x - pc.x;
  mrow[33] = ps.y - pc.y;
  mrow[34] = ps.z - pc.z;
  mrow[35] = ps.w - pc.w;
}

__global__ void zero_stats() {
  int t = threadIdx.x;
  g_sum[t] = 0.f;
  g_sqs[t] = 0.f;
}

template<int ID, int C>
__global__ void colstats(int rows) {
  const float* __restrict__ X = bufsel<ID>();
  int c = threadIdx.x;                    // blockDim == C
  float s = 0.f, q = 0.f;
  for (int r = blockIdx.x; r < rows; r += gridDim.x) {
    float v = X[(size_t)r * C + c];
    s += v; q += v * v;
  }
  atomicAdd(&g_sum[c], s);
  atomicAdd(&g_sqs[c], q);
}

// BN directly on the buffer whose stats were just computed: y = a*x + b
__global__ void param_bn(const float* __restrict__ g, const float* __restrict__ be,
                         float n, int C) {
  int c = threadIdx.x;
  if (c >= C) return;
  float mean = g_sum[c] / n;
  float var  = fmaxf(g_sqs[c] / n - mean * mean, 0.f);
  float a = g[c] * rsqrtf(var + EPS);
  g_cfa[c] = a;
  g_cfb[c] = be[c] - a * mean;
}

// BN of u = w*e + b_dw given stats of e (b_dw cancels): bn(u) = a*e + s
__global__ void param_dw(const float* __restrict__ w, const float* __restrict__ g,
                         const float* __restrict__ be, float n, int C) {
  int c = threadIdx.x;
  if (c >= C) return;
  float mean = g_sum[c] / n;
  float var  = fmaxf(g_sqs[c] / n - mean * mean, 0.f);
  float r = rsqrtf(w[c] * w[c] * var + EPS);
  float a = w[c] * r * g[c];
  g_cfa[c] = a;
  g_cfb[c] = be[c] - a * mean;
}

template<int ID, int C, bool RELU>
__global__ void ew_affine(size_t total) {
  float* __restrict__ X = bufsel<ID>();
  size_t stride = (size_t)gridDim.x * blockDim.x;
  for (size_t i = (size_t)blockIdx.x * blockDim.x + threadIdx.x; i < total; i += stride) {
    int c = (int)(i & (C - 1));
    float v = g_cfa[c] * X[i] + g_cfb[c];
    if (RELU) v = fmaxf(v, 0.f);
    X[i] = v;
  }
}

// agg[m][c] = max_e bn(pre3[m*16+e][c])  (affine applied per element: sign-safe)
__global__ void segmax_kernel() {
  int i = blockIdx.x * blockDim.x + threadIdx.x;
  if (i >= NM * 128) return;
  int c = i & 127;
  int m = i >> 7;
  size_t base = (size_t)m * 16 * 128 + c;
  float a = g_cfa[c], b = g_cfb[c];
  float mv = -INFINITY;
#pragma unroll
  for (int e = 0; e < 16; e++)
    mv = fmaxf(mv, fmaf(a, g_pre3[base + (size_t)e * 128], b));
  g_agg[i] = mv;
}

__global__ void final_out(float* __restrict__ out) {
  int i = blockIdx.x * blockDim.x + threadIdx.x;
  if (i >= NM * 128) return;
  int c = i & 127;
  float v = g_cfa[c] * g_obuf[i] + g_cfb[c] + g_agg[i];
  out[i] = fmaxf(v, 0.f);
}

// ---------------- f32 tiled GEMM: out[M,N] = pro(A[M,K]) @ B[K,N] + bias ----
// 64x64 tile, 256 threads, 4x4 micro-tile per thread.
template<int AID, int OID, bool PRO_AFF, bool PRO_RELU, bool EPI_RELU>
__launch_bounds__(256)
__global__ void gemm_f32(const float* __restrict__ B, const float* __restrict__ bias,
                         int Mrows, int Ncols, int Kdim) {
  const float* __restrict__ A = bufsel<AID>();
  float* __restrict__ Out = bufsel<OID>();
  __shared__ float As[16][68];
  __shared__ float Bs[16][68];
  const int tid = threadIdx.x;
  const int tx = tid & 15, ty = tid >> 4;
  const int m0 = blockIdx.x * 64;
  const int n0 = blockIdx.y * 64;

  float acc[4][4];
#pragma unroll
  for (int i = 0; i < 4; i++)
#pragma unroll
    for (int j = 0; j < 4; j++) acc[i][j] = 0.f;

  const int arow = tid >> 2;          // 0..63
  const int akq  = (tid & 3) * 4;     // 0,4,8,12
  const int brow = tid >> 4;          // 0..15
  const int bnq  = (tid & 15) * 4;    // 0..60

  for (int k0 = 0; k0 < Kdim; k0 += 16) {
    // A tile (with optional per-K-channel affine/relu prologue)
    {
      float4 v = make_float4(0.f, 0.f, 0.f, 0.f);
      int gr = m0 + arow;
      int gk = k0 + akq;
      if (gr < Mrows && gk + 3 < Kdim) {
        v = *reinterpret_cast<const float4*>(A + (size_t)gr * Kdim + gk);
        if (PRO_AFF) {
          v.x = fmaf(g_cfa[gk+0], v.x, g_cfb[gk+0]);
          v.y = fmaf(g_cfa[gk+1], v.y, g_cfb[gk+1]);
          v.z = fmaf(g_cfa[gk+2], v.z, g_cfb[gk+2]);
          v.w = fmaf(g_cfa[gk+3], v.w, g_cfb[gk+3]);
        }
        if (PRO_RELU) {
          v.x = fmaxf(v.x, 0.f); v.y = fmaxf(v.y, 0.f);
          v.z = fmaxf(v.z, 0.f); v.w = fmaxf(v.w, 0.f);
        }
      }
      As[akq+0][arow] = v.x;
      As[akq+1][arow] = v.y;
      As[akq+2][arow] = v.z;
      As[akq+3][arow] = v.w;
    }
    // B tile
    {
      float4 v = make_float4(0.f, 0.f, 0.f, 0.f);
      int gk = k0 + brow;
      if (gk < Kdim)
        v = *reinterpret_cast<const float4*>(B + (size_t)gk * Ncols + n0 + bnq);
      *reinterpret_cast<float4*>(&Bs[brow][bnq]) = v;
    }
    __syncthreads();
#pragma unroll
    for (int kk = 0; kk < 16; kk++) {
      float4 a4 = *reinterpret_cast<const float4*>(&As[kk][ty*4]);
      float4 b4 = *reinterpret_cast<const float4*>(&Bs[kk][tx*4]);
      float av[4] = {a4.x, a4.y, a4.z, a4.w};
      float bv[4] = {b4.x, b4.y, b4.z, b4.w};
#pragma unroll
      for (int i = 0; i < 4; i++)
#pragma unroll
        for (int j = 0; j < 4; j++)
          acc[i][j] = fmaf(av[i], bv[j], acc[i][j]);
    }
    __syncthreads();
  }
#pragma unroll
  for (int i = 0; i < 4; i++) {
    int gr = m0 + ty*4 + i;
    if (gr >= Mrows) break;
    float4 v;
    int gc = n0 + tx*4;
    v.x = acc[i][0] + bias[gc+0];
    v.y = acc[i][1] + bias[gc+1];
    v.z = acc[i][2] + bias[gc+2];
    v.w = acc[i][3] + bias[gc+3];
    if (EPI_RELU) {
      v.x = fmaxf(v.x, 0.f); v.y = fmaxf(v.y, 0.f);
      v.z = fmaxf(v.z, 0.f); v.w = fmaxf(v.w, 0.f);
    }
    *reinterpret_cast<float4*>(Out + (size_t)gr * Ncols + gc) = v;
  }
}

// ---------------- host launch ----------------------------------------------
extern "C" void kernel_launch(void* const* d_in, const int* in_sizes, int n_in,
                              void* d_out, int out_size, void* d_ws, size_t ws_size,
                              hipStream_t stream) {
  const float* x     = (const float*)d_in[0];
  const float* pos   = (const float*)d_in[1];
  const int*   batch = (const int*)  d_in[2];
  const float* refl  = (const float*)d_in[3];
  const float* sf    = (const float*)d_in[4];
  const int*   idx   = (const int*)  d_in[5];
  const int*   esrc  = (const int*)  d_in[6];
  const int*   edst  = (const int*)  d_in[7];
  const float* W1  = (const float*)d_in[8];
  const float* b1  = (const float*)d_in[9];
  const float* W2  = (const float*)d_in[10];
  const float* b2  = (const float*)d_in[11];
  const float* g2  = (const float*)d_in[12];
  const float* be2 = (const float*)d_in[13];
  const float* W3  = (const float*)d_in[14];
  const float* b3  = (const float*)d_in[15];
  const float* g3  = (const float*)d_in[16];
  const float* be3 = (const float*)d_in[17];
  // 18..23: ryn_* unused (gate == 1 exactly)
  const float* expW  = (const float*)d_in[24];
  const float* expb  = (const float*)d_in[25];
  const float* expg  = (const float*)d_in[26];
  const float* expbe = (const float*)d_in[27];
  const float* dww  = (const float*)d_in[28];
  const float* dwg  = (const float*)d_in[30];
  const float* dwbe = (const float*)d_in[31];
  const float* pwW  = (const float*)d_in[32];
  const float* pwb  = (const float*)d_in[33];
  const float* pwg  = (const float*)d_in[34];
  const float* pwbe = (const float*)d_in[35];
  const float* cg   = (const float*)d_in[36];
  const float* cbe  = (const float*)d_in[37];
  const float* projW  = (const float*)d_in[38];
  const float* projb  = (const float*)d_in[39];
  const float* projg  = (const float*)d_in[40];
  const float* projbe = (const float*)d_in[41];
  float* out = (float*)d_out;

  const float fNE = (float)NE, fNM = (float)NM;
  const int SG = 2048;  // colstats grid

  prep_pos<<<(NP + 255) / 256, 256, 0, stream>>>(pos, batch, refl, sf);
  tail_out<<<(NM + 255) / 256, 256, 0, stream>>>(pos, batch, refl, sf, idx, out);
  gather_msg<<<(NE + 255) / 256, 256, 0, stream>>>(x, esrc, edst, idx);

  // h1 = relu(msg @ W1 + b1)     [E,36] -> [E,64]
  gemm_f32<0, 1, false, false, true><<<dim3(NE/64, 1), 256, 0, stream>>>(W1, b1, NE, 64, 36);
  // pre2 = relu(h1 @ W2 + b2)    [E,64] -> [E,64]
  gemm_f32<1, 2, false, false, true><<<dim3(NE/64, 1), 256, 0, stream>>>(W2, b2, NE, 64, 64);
  zero_stats<<<1, 512, 0, stream>>>();
  colstats<2, 64><<<SG, 64, 0, stream>>>(NE);
  param_bn<<<1, 64, 0, stream>>>(g2, be2, fNE, 64);
  // pre3 = relu(bn(pre2) @ W3 + b3)   [E,64] -> [E,128]
  gemm_f32<2, 3, true, false, true><<<dim3(NE/64, 2), 256, 0, stream>>>(W3, b3, NE, 128, 64);
  zero_stats<<<1, 512, 0, stream>>>();
  colstats<3, 128><<<SG, 128, 0, stream>>>(NE);
  param_bn<<<1, 128, 0, stream>>>(g3, be3, fNE, 128);
  // agg = max over 16 edges of bn(pre3)
  segmax_kernel<<<(NM*128 + 255)/256, 256, 0, stream>>>();

  // t1 = agg @ exp_W + exp_b    [M,128] -> [M,512]
  gemm_f32<4, 5, false, false, false><<<dim3((NM+63)/64, 8), 256, 0, stream>>>(expW, expb, NM, 512, 128);
  zero_stats<<<1, 512, 0, stream>>>();
  colstats<5, 512><<<SG, 512, 0, stream>>>(NM);
  param_bn<<<1, 512, 0, stream>>>(expg, expbe, fNM, 512);
  // e = relu(bn(t1)) in place
  ew_affine<5, 512, true><<<4096, 256, 0, stream>>>((size_t)NM * 512);
  zero_stats<<<1, 512, 0, stream>>>();
  colstats<5, 512><<<SG, 512, 0, stream>>>(NM);
  param_dw<<<1, 512, 0, stream>>>(dww + 0, dwg + 0, dwbe + 0, fNM, 512);
  // p0 = relu(bn(e*dw0)) @ pw_W0 + pw_b0   (d0 fused as A-prologue)
  gemm_f32<5, 6, true, true, false><<<dim3((NM+63)/64, 8), 256, 0, stream>>>(pwW + 0, pwb + 0, NM, 512, 512);
  zero_stats<<<1, 512, 0, stream>>>();
  colstats<6, 512><<<SG, 512, 0, stream>>>(NM);
  param_bn<<<1, 512, 0, stream>>>(pwg + 0, pwbe + 0, fNM, 512);
  // v0 = relu(bn(p0)) in place
  ew_affine<6, 512, true><<<4096, 256, 0, stream>>>((size_t)NM * 512);
  zero_stats<<<1, 512, 0, stream>>>();
  colstats<6, 512><<<SG, 512, 0, stream>>>(NM);
  param_bn<<<1, 512, 0, stream>>>(cg + 0, cbe + 0, fNM, 512);
  // cmid = relu(bn(v0)) in place
  ew_affine<6, 512, true><<<4096, 256, 0, stream>>>((size_t)NM * 512);
  zero_stats<<<1, 512, 0, stream>>>();
  colstats<6, 512><<<SG, 512, 0, stream>>>(NM);
  param_dw<<<1, 512, 0, stream>>>(dww + 512, dwg + 512, dwbe + 512, fNM, 512);
  // p1 = relu(bn(cmid*dw1)) @ pw_W1 + pw_b1
  gemm_f32<6, 5, true, true, false><<<dim3((NM+63)/64, 8), 256, 0, stream>>>(pwW + 512*512, pwb + 512, NM, 512, 512);
  zero_stats<<<1, 512, 0, stream>>>();
  colstats<5, 512><<<SG, 512, 0, stream>>>(NM);
  param_bn<<<1, 512, 0, stream>>>(pwg + 512, pwbe + 512, fNM, 512);
  // v1 = relu(bn(p1)) in place
  ew_affine<5, 512, true><<<4096, 256, 0, stream>>>((size_t)NM * 512);
  zero_stats<<<1, 512, 0, stream>>>();
  colstats<5, 512><<<SG, 512, 0, stream>>>(NM);
  param_bn<<<1, 512, 0, stream>>>(cg + 512, cbe + 512, fNM, 512);
  // o_raw = bn(v1) @ proj_W + proj_b  (cmid2 affine fused, no relu)
  gemm_f32<5, 7, true, false, false><<<dim3((NM+63)/64, 2), 256, 0, stream>>>(projW, projb, NM, 128, 512);
  zero_stats<<<1, 512, 0, stream>>>();
  colstats<7, 128><<<SG, 128, 0, stream>>>(NM);
  param_bn<<<1, 128, 0, stream>>>(projg, projbe, fNM, 128);
  // out = relu(bn(o_raw) + agg)
  final_out<<<(NM*128 + 255)/256, 256, 0, stream>>>(out);
}

// Round 2
// 949.713 us; speedup vs baseline: 3.1211x; 3.1211x over previous
//
#include <hip/hip_runtime.h>
#include <hip/hip_bf16.h>
#include <cstdint>

#define DEV_INLINE __device__ __forceinline__

typedef unsigned short u16;
typedef unsigned int   u32;
typedef short bf16x8 __attribute__((ext_vector_type(8)));
typedef float f32x4  __attribute__((ext_vector_type(4)));

constexpr int NP = 120000, NB = 8, NM = 60000, KNN = 16;
constexpr int NE = NM * KNN;          // 960000
constexpr float EPS = 1e-5f;

constexpr size_t O_POS   = (size_t)NM * 128;
constexpr size_t O_BATCH = O_POS + (size_t)NM * 3;
constexpr size_t O_REFL  = O_BATCH + NM;
constexpr size_t O_SF    = O_REFL + NM;

// ---------------- device-global buffers -------------------------------------
__device__ float  g_pos_s[(size_t)NP * 4];
__device__ u16    g_pre2[(size_t)NE * 64];        // bf16
__device__ float  g_aggmax[(size_t)NM * 128];
__device__ float  g_aggmin[(size_t)NM * 128];
__device__ float  g_agg[(size_t)NM * 128];        // f32 residual
__device__ u16    g_aggbf[(size_t)NM * 128];      // bf16 GEMM input
__device__ u16    g_bufA[(size_t)NM * 512];
__device__ u16    g_bufB[(size_t)NM * 512];
__device__ float  g_obuf[(size_t)NM * 128];
__device__ float  g_sum[512], g_sqs[512], g_cfa[512], g_cfb[512];
// transposed bf16 weights [N][K]
__device__ u16 g_w1t[64 * 64];      // K padded 36->64 (zeros)
__device__ u16 g_w2t[64 * 64];
__device__ u16 g_w3t[128 * 64];
__device__ u16 g_expwt[512 * 128];
__device__ u16 g_pw0t[512 * 512];
__device__ u16 g_pw1t[512 * 512];
__device__ u16 g_projwt[128 * 512];

template<int ID> DEV_INLINE const u16* ubufsel() {
  if constexpr (ID == 1) return g_aggbf;
  else if constexpr (ID == 2) return g_bufA;
  else return g_bufB;
}
template<int ID> DEV_INLINE u16* obufsel() {
  if constexpr (ID == 2) return g_bufA;
  else return g_bufB;
}
template<int ID> DEV_INLINE const u16* wsel() {
  if constexpr (ID == 3) return g_expwt;
  else if constexpr (ID == 4) return g_pw0t;
  else if constexpr (ID == 5) return g_pw1t;
  else return g_projwt;
}

// ---------------- helpers ----------------------------------------------------
DEV_INLINE float bf2f(u16 u) { u32 x = (u32)u << 16; float f; __builtin_memcpy(&f, &x, 4); return f; }
DEV_INLINE u16 f2bf(float f) {
  u32 x; __builtin_memcpy(&x, &f, 4);
  return (u16)((x + 0x7FFFu + ((x >> 16) & 1u)) >> 16);
}
DEV_INLINE u32 pack2(float a, float b) { return (u32)f2bf(a) | ((u32)f2bf(b) << 16); }

// affine (+optional relu) on 8 packed bf16, channels kbase..kbase+7
DEV_INLINE uint4 affine8(uint4 v, int kbase, bool relu) {
  u32 u[4] = {v.x, v.y, v.z, v.w};
  u32 r[4];
#pragma unroll
  for (int q = 0; q < 4; q++) {
    float lo = bf2f((u16)(u[q] & 0xFFFFu));
    float hi = bf2f((u16)(u[q] >> 16));
    lo = fmaf(g_cfa[kbase + 2*q],     lo, g_cfb[kbase + 2*q]);
    hi = fmaf(g_cfa[kbase + 2*q + 1], hi, g_cfb[kbase + 2*q + 1]);
    if (relu) { lo = fmaxf(lo, 0.f); hi = fmaxf(hi, 0.f); }
    r[q] = (u32)f2bf(lo) | ((u32)f2bf(hi) << 16);
  }
  return make_uint4(r[0], r[1], r[2], r[3]);
}

// ---------------- tiny kernels ----------------------------------------------
__global__ void prep_pos(const float* __restrict__ pos, const int* __restrict__ batch,
                         const float* __restrict__ refl, const float* __restrict__ sf) {
  int i = blockIdx.x * blockDim.x + threadIdx.x;
  if (i >= NP) return;
  float s = sf[batch[i]];
  float4 v;
  v.x = pos[(size_t)i*3+0] / s;
  v.y = pos[(size_t)i*3+1] / s;
  v.z = pos[(size_t)i*3+2] / s;
  v.w = refl[i];   // gate == 1 exactly
  *reinterpret_cast<float4*>(g_pos_s + (size_t)i*4) = v;
}

__global__ void tail_out(const float* __restrict__ pos, const int* __restrict__ batch,
                         const float* __restrict__ refl, const float* __restrict__ sf,
                         const int* __restrict__ idx, float* __restrict__ out) {
  int i = blockIdx.x * blockDim.x + threadIdx.x;
  if (i < NM) {
    int p = idx[i];
    out[O_POS + (size_t)i*3+0] = pos[(size_t)p*3+0];
    out[O_POS + (size_t)i*3+1] = pos[(size_t)p*3+1];
    out[O_POS + (size_t)i*3+2] = pos[(size_t)p*3+2];
    out[O_BATCH + i] = (float)batch[p];
    out[O_REFL  + i] = refl[p];
  }
  if (i < NB) out[O_SF + i] = sf[i];
}

__global__ void zero_stats() {
  int t = threadIdx.x;
  g_sum[t] = 0.f; g_sqs[t] = 0.f;
}

// transpose + bf16-convert all weights (one kernel)
__global__ void prep_weights(const float* __restrict__ W1, const float* __restrict__ W2,
                             const float* __restrict__ W3, const float* __restrict__ expW,
                             const float* __restrict__ pwW, const float* __restrict__ projW) {
  int i = blockIdx.x * 256 + threadIdx.x;
  // segment sizes
  const int s0 = 4096, s1 = 4096, s2 = 8192, s3 = 65536, s4 = 262144, s5 = 262144, s6 = 65536;
  if (i < s0) { int n = i >> 6, k = i & 63; g_w1t[i] = (k < 36) ? f2bf(W1[k*64 + n]) : (u16)0; return; }
  i -= s0;
  if (i < s1) { int n = i >> 6, k = i & 63; g_w2t[i] = f2bf(W2[k*64 + n]); return; }
  i -= s1;
  if (i < s2) { int n = i >> 6, k = i & 63; g_w3t[i] = f2bf(W3[k*128 + n]); return; }
  i -= s2;
  if (i < s3) { int n = i >> 7, k = i & 127; g_expwt[i] = f2bf(expW[k*512 + n]); return; }
  i -= s3;
  if (i < s4) { int n = i >> 9, k = i & 511; g_pw0t[i] = f2bf(pwW[k*512 + n]); return; }
  i -= s4;
  if (i < s5) { int n = i >> 9, k = i & 511; g_pw1t[i] = f2bf(pwW[262144 + k*512 + n]); return; }
  i -= s5;
  if (i < s6) { int n = i >> 9, k = i & 511; g_projwt[i] = f2bf(projW[k*128 + n]); return; }
}

// param: BN of buffer whose stats are in g_sum/g_sqs; then zero stats for next user
__global__ void param_bn(const float* __restrict__ g, const float* __restrict__ be,
                         float n, int C) {
  int c = threadIdx.x;
  if (c < C) {
    float mean = g_sum[c] / n;
    float var  = fmaxf(g_sqs[c] / n - mean * mean, 0.f);
    float a = g[c] * rsqrtf(var + EPS);
    g_cfa[c] = a;
    g_cfb[c] = be[c] - a * mean;
  }
  __syncthreads();
  g_sum[c] = 0.f; g_sqs[c] = 0.f;
}

// BN of u = w*h + b_dw given stats of h (b_dw cancels)
__global__ void param_dw(const float* __restrict__ w, const float* __restrict__ g,
                         const float* __restrict__ be, float n, int C) {
  int c = threadIdx.x;
  if (c < C) {
    float mean = g_sum[c] / n;
    float var  = fmaxf(g_sqs[c] / n - mean * mean, 0.f);
    float r = rsqrtf(w[c]*w[c]*var + EPS);
    float a = w[c] * r * g[c];
    g_cfa[c] = a;
    g_cfb[c] = be[c] - a * mean;
  }
  __syncthreads();
  g_sum[c] = 0.f; g_sqs[c] = 0.f;
}

// ---------------- K1: fused gather + MLP1 + MLP2 (128 edges/block) ----------
__launch_bounds__(256)
__global__ void k1_edge(const float* __restrict__ x, const int* __restrict__ esrc,
                        const int* __restrict__ idx,
                        const float* __restrict__ b1, const float* __restrict__ b2) {
  __shared__ u16 sMsg[128][72];
  __shared__ u16 sH[128][72];
  __shared__ u16 sW1[64][72];
  __shared__ u16 sW2[64][72];
  __shared__ float ssum[64], ssqs[64];
  const int tid = threadIdx.x;
  const int e0 = blockIdx.x * 128;
  if (tid < 64) { ssum[tid] = 0.f; ssqs[tid] = 0.f; }
  // stage weights
  {
    int row = tid >> 2, seg = tid & 3;
    const uint4* p1 = reinterpret_cast<const uint4*>(g_w1t + row*64 + seg*16);
    const uint4* p2 = reinterpret_cast<const uint4*>(g_w2t + row*64 + seg*16);
    uint4 a0 = p1[0], a1 = p1[1], c0 = p2[0], c1 = p2[1];
    *reinterpret_cast<uint4*>(&sW1[row][seg*16])   = a0;
    *reinterpret_cast<uint4*>(&sW1[row][seg*16+8]) = a1;
    *reinterpret_cast<uint4*>(&sW2[row][seg*16])   = c0;
    *reinterpret_cast<uint4*>(&sW2[row][seg*16+8]) = c1;
  }
  // gather msg tile
  {
    int e = tid >> 1, half = tid & 1;
    int ge = e0 + e;
    int s = esrc[ge];
    const float4* xs = reinterpret_cast<const float4*>(x + (size_t)s * 32);
    if (half == 0) {
      float4 v0 = xs[0], v1 = xs[1], v2 = xs[2], v3 = xs[3];
      uint4 u0 = make_uint4(pack2(v0.x,v0.y), pack2(v0.z,v0.w), pack2(v1.x,v1.y), pack2(v1.z,v1.w));
      uint4 u1 = make_uint4(pack2(v2.x,v2.y), pack2(v2.z,v2.w), pack2(v3.x,v3.y), pack2(v3.z,v3.w));
      *reinterpret_cast<uint4*>(&sMsg[e][0]) = u0;
      *reinterpret_cast<uint4*>(&sMsg[e][8]) = u1;
    } else {
      float4 v0 = xs[4], v1 = xs[5], v2 = xs[6], v3 = xs[7];
      uint4 u0 = make_uint4(pack2(v0.x,v0.y), pack2(v0.z,v0.w), pack2(v1.x,v1.y), pack2(v1.z,v1.w));
      uint4 u1 = make_uint4(pack2(v2.x,v2.y), pack2(v2.z,v2.w), pack2(v3.x,v3.y), pack2(v3.z,v3.w));
      *reinterpret_cast<uint4*>(&sMsg[e][16]) = u0;
      *reinterpret_cast<uint4*>(&sMsg[e][24]) = u1;
      int c = idx[ge >> 4];   // edge_dst == repeat(arange(M), 16)
      float4 ps = *reinterpret_cast<const float4*>(g_pos_s + (size_t)s * 4);
      float4 pc = *reinterpret_cast<const float4*>(g_pos_s + (size_t)c * 4);
      uint4 ur = make_uint4(pack2(ps.x-pc.x, ps.y-pc.y), pack2(ps.z-pc.z, ps.w-pc.w), 0u, 0u);
      *reinterpret_cast<uint4*>(&sMsg[e][32]) = ur;
      *reinterpret_cast<uint4*>(&sMsg[e][40]) = make_uint4(0,0,0,0);
      *reinterpret_cast<uint4*>(&sMsg[e][48]) = make_uint4(0,0,0,0);
      *reinterpret_cast<uint4*>(&sMsg[e][56]) = make_uint4(0,0,0,0);
    }
  }
  __syncthreads();
  const int w = tid >> 6, lane = tid & 63, l15 = lane & 15, l4 = lane >> 4;
  // gemm1: h1 = relu(msg @ W1 + b1)   (wave: 32 rows x 64 cols)
  f32x4 acc1[2][4] = {};
#pragma unroll
  for (int ks = 0; ks < 2; ks++) {
    bf16x8 a0 = *reinterpret_cast<const bf16x8*>(&sMsg[w*32 + l15][ks*32 + l4*8]);
    bf16x8 a1 = *reinterpret_cast<const bf16x8*>(&sMsg[w*32 + 16 + l15][ks*32 + l4*8]);
#pragma unroll
    for (int fc = 0; fc < 4; fc++) {
      bf16x8 bb = *reinterpret_cast<const bf16x8*>(&sW1[fc*16 + l15][ks*32 + l4*8]);
      acc1[0][fc] = __builtin_amdgcn_mfma_f32_16x16x32_bf16(a0, bb, acc1[0][fc], 0, 0, 0);
      acc1[1][fc] = __builtin_amdgcn_mfma_f32_16x16x32_bf16(a1, bb, acc1[1][fc], 0, 0, 0);
    }
  }
#pragma unroll
  for (int fc = 0; fc < 4; fc++) {
    float bv = b1[fc*16 + l15];
#pragma unroll
    for (int fr = 0; fr < 2; fr++)
#pragma unroll
      for (int r = 0; r < 4; r++) {
        float v = fmaxf(acc1[fr][fc][r] + bv, 0.f);
        sH[w*32 + fr*16 + l4*4 + r][fc*16 + l15] = f2bf(v);
      }
  }
  __syncthreads();
  // gemm2: pre2 = relu(h1 @ W2 + b2)
  f32x4 acc2[2][4] = {};
#pragma unroll
  for (int ks = 0; ks < 2; ks++) {
    bf16x8 a0 = *reinterpret_cast<const bf16x8*>(&sH[w*32 + l15][ks*32 + l4*8]);
    bf16x8 a1 = *reinterpret_cast<const bf16x8*>(&sH[w*32 + 16 + l15][ks*32 + l4*8]);
#pragma unroll
    for (int fc = 0; fc < 4; fc++) {
      bf16x8 bb = *reinterpret_cast<const bf16x8*>(&sW2[fc*16 + l15][ks*32 + l4*8]);
      acc2[0][fc] = __builtin_amdgcn_mfma_f32_16x16x32_bf16(a0, bb, acc2[0][fc], 0, 0, 0);
      acc2[1][fc] = __builtin_amdgcn_mfma_f32_16x16x32_bf16(a1, bb, acc2[1][fc], 0, 0, 0);
    }
  }
  // epilogue: relu + stats + bounce (reuse sMsg) + coalesced store
#pragma unroll
  for (int fc = 0; fc < 4; fc++) {
    float bv = b2[fc*16 + l15];
    float s = 0.f, q = 0.f;
#pragma unroll
    for (int fr = 0; fr < 2; fr++)
#pragma unroll
      for (int r = 0; r < 4; r++) {
        float v = fmaxf(acc2[fr][fc][r] + bv, 0.f);
        s += v; q += v*v;
        sMsg[w*32 + fr*16 + l4*4 + r][fc*16 + l15] = f2bf(v);
      }
    atomicAdd(&ssum[fc*16 + l15], s);
    atomicAdd(&ssqs[fc*16 + l15], q);
  }
  __syncthreads();
  if (tid < 64) { atomicAdd(&g_sum[tid], ssum[tid]); atomicAdd(&g_sqs[tid], ssqs[tid]); }
  {
    int row = tid >> 1, seg = tid & 1;
    const uint4* src = reinterpret_cast<const uint4*>(&sMsg[row][seg*32]);
    uint4 d0 = src[0], d1 = src[1], d2 = src[2], d3 = src[3];
    uint4* dst = reinterpret_cast<uint4*>(g_pre2 + (size_t)(e0 + row)*64 + seg*32);
    dst[0] = d0; dst[1] = d1; dst[2] = d2; dst[3] = d3;
  }
}

// ---------------- K2: MLP3 + stats + per-center max/min (pre3 never stored) --
__launch_bounds__(256)
__global__ void k2_edge(const float* __restrict__ b3) {
  __shared__ u16 sA[128][72];
  __shared__ u16 sB[128][72];
  __shared__ float ssum[128], ssqs[128];
  const int tid = threadIdx.x;
  const int e0 = blockIdx.x * 128;
  if (tid < 128) { ssum[tid] = 0.f; ssqs[tid] = 0.f; }
  {
    int row = tid >> 1, seg = tid & 1;
    const uint4* p = reinterpret_cast<const uint4*>(g_pre2 + (size_t)(e0 + row)*64 + seg*32);
    uint4 v0 = p[0], v1 = p[1], v2 = p[2], v3 = p[3];
    v0 = affine8(v0, seg*32 + 0,  false);
    v1 = affine8(v1, seg*32 + 8,  false);
    v2 = affine8(v2, seg*32 + 16, false);
    v3 = affine8(v3, seg*32 + 24, false);
    uint4* d = reinterpret_cast<uint4*>(&sA[row][seg*32]);
    d[0] = v0; d[1] = v1; d[2] = v2; d[3] = v3;
  }
  {
    int row = tid >> 1, seg = tid & 1;
    const uint4* p = reinterpret_cast<const uint4*>(g_w3t + row*64 + seg*32);
    uint4 v0 = p[0], v1 = p[1], v2 = p[2], v3 = p[3];
    uint4* d = reinterpret_cast<uint4*>(&sB[row][seg*32]);
    d[0] = v0; d[1] = v1; d[2] = v2; d[3] = v3;
  }
  __syncthreads();
  const int wave = tid >> 6, lane = tid & 63, l15 = lane & 15, l4 = lane >> 4;
  const int wr = wave >> 1, wc = wave & 1;
  f32x4 acc[4][4] = {};
#pragma unroll
  for (int ks = 0; ks < 2; ks++) {
    bf16x8 af[4], bf[4];
#pragma unroll
    for (int fr = 0; fr < 4; fr++)
      af[fr] = *reinterpret_cast<const bf16x8*>(&sA[wr*64 + fr*16 + l15][ks*32 + l4*8]);
#pragma unroll
    for (int fc = 0; fc < 4; fc++)
      bf[fc] = *reinterpret_cast<const bf16x8*>(&sB[wc*64 + fc*16 + l15][ks*32 + l4*8]);
#pragma unroll
    for (int fr = 0; fr < 4; fr++)
#pragma unroll
      for (int fc = 0; fc < 4; fc++)
        acc[fr][fc] = __builtin_amdgcn_mfma_f32_16x16x32_bf16(af[fr], bf[fc], acc[fr][fc], 0, 0, 0);
  }
#pragma unroll
  for (int fc = 0; fc < 4; fc++) {
    float bv = b3[wc*64 + fc*16 + l15];
    float s = 0.f, q = 0.f;
#pragma unroll
    for (int fr = 0; fr < 4; fr++) {
      float mx = -1e30f, mn = 1e30f;
#pragma unroll
      for (int r = 0; r < 4; r++) {
        float v = fmaxf(acc[fr][fc][r] + bv, 0.f);
        s += v; q += v*v;
        mx = fmaxf(mx, v); mn = fminf(mn, v);
      }
      mx = fmaxf(mx, __shfl_xor(mx, 16, 64)); mx = fmaxf(mx, __shfl_xor(mx, 32, 64));
      mn = fminf(mn, __shfl_xor(mn, 16, 64)); mn = fminf(mn, __shfl_xor(mn, 32, 64));
      if (l4 == 0) {
        int m = blockIdx.x * 8 + wr*4 + fr;
        g_aggmax[(size_t)m*128 + wc*64 + fc*16 + l15] = mx;
        g_aggmin[(size_t)m*128 + wc*64 + fc*16 + l15] = mn;
      }
    }
    atomicAdd(&ssum[wc*64 + fc*16 + l15], s);
    atomicAdd(&ssqs[wc*64 + fc*16 + l15], q);
  }
  __syncthreads();
  if (tid < 128) { atomicAdd(&g_sum[tid], ssum[tid]); atomicAdd(&g_sqs[tid], ssqs[tid]); }
}

// K3: agg = bn3-affine of max/min (sign-select); write f32 residual + bf16
__global__ void k3_agg() {
  int i4 = (blockIdx.x * 256 + threadIdx.x) * 4;
  if (i4 >= NM * 128) return;
  int c = i4 & 127;
  float4 mx = *reinterpret_cast<const float4*>(g_aggmax + i4);
  float4 mn = *reinterpret_cast<const float4*>(g_aggmin + i4);
  float4 a  = *reinterpret_cast<const float4*>(g_cfa + c);
  float4 b  = *reinterpret_cast<const float4*>(g_cfb + c);
  float v0 = a.x > 0.f ? fmaf(a.x, mx.x, b.x) : fmaf(a.x, mn.x, b.x);
  float v1 = a.y > 0.f ? fmaf(a.y, mx.y, b.y) : fmaf(a.y, mn.y, b.y);
  float v2 = a.z > 0.f ? fmaf(a.z, mx.z, b.z) : fmaf(a.z, mn.z, b.z);
  float v3 = a.w > 0.f ? fmaf(a.w, mx.w, b.w) : fmaf(a.w, mn.w, b.w);
  *reinterpret_cast<float4*>(g_agg + i4) = make_float4(v0, v1, v2, v3);
  uint2 pk; pk.x = pack2(v0, v1); pk.y = pack2(v2, v3);
  *reinterpret_cast<uint2*>(g_aggbf + i4) = pk;
}

// ---------------- MFMA GEMM: Out[M,N] = PRO(A[M,K]) @ Bt[N,K]^T + bias ------
// 128x128 tile, 256 thr (4 waves 2x2), BK=32, fused column-stats epilogue.
template<int AID, int WID, int OID, bool PRO_AFF, bool PRO_RELU, bool OUT_BF16>
__launch_bounds__(256)
__global__ void gemm_mfma(const float* __restrict__ bias, int Mrows, int Ncols, int Kdim) {
  const u16* __restrict__ A  = ubufsel<AID>();
  const u16* __restrict__ Bt = wsel<WID>();
  __shared__ u16 As[128][40];
  __shared__ u16 Bs[128][40];
  __shared__ float ssum[128], ssqs[128];
  const int tid = threadIdx.x;
  const int m0 = blockIdx.x * 128, n0 = blockIdx.y * 128;
  if (tid < 128) { ssum[tid] = 0.f; ssqs[tid] = 0.f; }
  const int wave = tid >> 6, lane = tid & 63, l15 = lane & 15, l4 = lane >> 4;
  const int wr = wave >> 1, wc = wave & 1;
  const int srow = tid >> 1, sseg = tid & 1;
  const int gr = m0 + srow;
  const bool aval = gr < Mrows;
  f32x4 acc[4][4] = {};
  for (int k0 = 0; k0 < Kdim; k0 += 32) {
    uint4 va0 = make_uint4(0,0,0,0), va1 = va0;
    if (aval) {
      const uint4* p = reinterpret_cast<const uint4*>(A + (size_t)gr*Kdim + k0 + sseg*16);
      va0 = p[0]; va1 = p[1];
    }
    if (PRO_AFF) {
      va0 = affine8(va0, k0 + sseg*16,     PRO_RELU);
      va1 = affine8(va1, k0 + sseg*16 + 8, PRO_RELU);
    }
    const uint4* pb = reinterpret_cast<const uint4*>(Bt + (size_t)(n0 + srow)*Kdim + k0 + sseg*16);
    uint4 vb0 = pb[0], vb1 = pb[1];
    __syncthreads();   // protect previous iteration's fragment reads
    *reinterpret_cast<uint4*>(&As[srow][sseg*16])     = va0;
    *reinterpret_cast<uint4*>(&As[srow][sseg*16 + 8]) = va1;
    *reinterpret_cast<uint4*>(&Bs[srow][sseg*16])     = vb0;
    *reinterpret_cast<uint4*>(&Bs[srow][sseg*16 + 8]) = vb1;
    __syncthreads();
    bf16x8 af[4], bf[4];
#pragma unroll
    for (int fr = 0; fr < 4; fr++)
      af[fr] = *reinterpret_cast<const bf16x8*>(&As[wr*64 + fr*16 + l15][l4*8]);
#pragma unroll
    for (int fc = 0; fc < 4; fc++)
      bf[fc] = *reinterpret_cast<const bf16x8*>(&Bs[wc*64 + fc*16 + l15][l4*8]);
#pragma unroll
    for (int fr = 0; fr < 4; fr++)
#pragma unroll
      for (int fc = 0; fc < 4; fc++)
        acc[fr][fc] = __builtin_amdgcn_mfma_f32_16x16x32_bf16(af[fr], bf[fc], acc[fr][fc], 0, 0, 0);
  }
  // epilogue: bias + stats + store
  const int orow = m0 + wr*64 + l4*4;
#pragma unroll
  for (int fc = 0; fc < 4; fc++) {
    int col = n0 + wc*64 + fc*16 + l15;
    float bv = bias[col];
    float s = 0.f, q = 0.f;
#pragma unroll
    for (int fr = 0; fr < 4; fr++)
#pragma unroll
      for (int r = 0; r < 4; r++) {
        int row = orow + fr*16 + r;
        if (row < Mrows) {
          float v = acc[fr][fc][r] + bv;
          s += v; q += v*v;
          if (OUT_BF16) obufsel<OID>()[(size_t)row*Ncols + col] = f2bf(v);
          else          g_obuf[(size_t)row*Ncols + col] = v;
        }
      }
    atomicAdd(&ssum[wc*64 + fc*16 + l15], s);
    atomicAdd(&ssqs[wc*64 + fc*16 + l15], q);
  }
  __syncthreads();
  if (tid < 128) { atomicAdd(&g_sum[n0 + tid], ssum[tid]); atomicAdd(&g_sqs[n0 + tid], ssqs[tid]); }
}

// ---------------- EW: y = relu(a*x+b) (bf16->bf16) + fused stats -------------
template<int INID, int OUTID>
__launch_bounds__(256)
__global__ void ew_stats(int rows) {
  const u16* __restrict__ X = ubufsel<INID>();
  u16* __restrict__ Y = obufsel<OUTID>();
  __shared__ float ssum[512], ssqs[512];
  const int tid = threadIdx.x;
  ssum[tid] = 0.f; ssum[tid+256] = 0.f; ssqs[tid] = 0.f; ssqs[tid+256] = 0.f;
  __syncthreads();
  const int c0 = (tid & 63) * 8;
  const int rl = tid >> 6;
  float a[8], b[8];
#pragma unroll
  for (int j = 0; j < 8; j++) { a[j] = g_cfa[c0+j]; b[j] = g_cfb[c0+j]; }
  float s[8] = {}, q[8] = {};
  for (int r = blockIdx.x*4 + rl; r < rows; r += gridDim.x*4) {
    uint4 v = *reinterpret_cast<const uint4*>(X + (size_t)r*512 + c0);
    u32 u[4] = {v.x, v.y, v.z, v.w}, o[4];
#pragma unroll
    for (int t = 0; t < 4; t++) {
      float lo = bf2f((u16)(u[t] & 0xFFFFu));
      float hi = bf2f((u16)(u[t] >> 16));
      lo = fmaxf(fmaf(a[2*t],   lo, b[2*t]),   0.f);
      hi = fmaxf(fmaf(a[2*t+1], hi, b[2*t+1]), 0.f);
      s[2*t] += lo; q[2*t] += lo*lo; s[2*t+1] += hi; q[2*t+1] += hi*hi;
      o[t] = (u32)f2bf(lo) | ((u32)f2bf(hi) << 16);
    }
    *reinterpret_cast<uint4*>(Y + (size_t)r*512 + c0) = make_uint4(o[0], o[1], o[2], o[3]);
  }
#pragma unroll
  for (int j = 0; j < 8; j++) { atomicAdd(&ssum[c0+j], s[j]); atomicAdd(&ssqs[c0+j], q[j]); }
  __syncthreads();
  atomicAdd(&g_sum[tid],     ssum[tid]);     atomicAdd(&g_sqs[tid],     ssqs[tid]);
  atomicAdd(&g_sum[tid+256], ssum[tid+256]); atomicAdd(&g_sqs[tid+256], ssqs[tid+256]);
}

__global__ void final_out(float* __restrict__ out) {
  int i4 = (blockIdx.x * 256 + threadIdx.x) * 4;
  if (i4 >= NM * 128) return;
  int c = i4 & 127;
  float4 o  = *reinterpret_cast<const float4*>(g_obuf + i4);
  float4 ag = *reinterpret_cast<const float4*>(g_agg + i4);
  float4 a  = *reinterpret_cast<const float4*>(g_cfa + c);
  float4 b  = *reinterpret_cast<const float4*>(g_cfb + c);
  float4 r;
  r.x = fmaxf(fmaf(a.x, o.x, b.x) + ag.x, 0.f);
  r.y = fmaxf(fmaf(a.y, o.y, b.y) + ag.y, 0.f);
  r.z = fmaxf(fmaf(a.z, o.z, b.z) + ag.z, 0.f);
  r.w = fmaxf(fmaf(a.w, o.w, b.w) + ag.w, 0.f);
  *reinterpret_cast<float4*>(out + i4) = r;
}

// ---------------- host launch ------------------------------------------------
extern "C" void kernel_launch(void* const* d_in, const int* in_sizes, int n_in,
                              void* d_out, int out_size, void* d_ws, size_t ws_size,
                              hipStream_t stream) {
  const float* x     = (const float*)d_in[0];
  const float* pos   = (const float*)d_in[1];
  const int*   batch = (const int*)  d_in[2];
  const float* refl  = (const float*)d_in[3];
  const float* sf    = (const float*)d_in[4];
  const int*   idx   = (const int*)  d_in[5];
  const int*   esrc  = (const int*)  d_in[6];
  const float* W1  = (const float*)d_in[8];
  const float* b1  = (const float*)d_in[9];
  const float* W2  = (const float*)d_in[10];
  const float* b2  = (const float*)d_in[11];
  const float* g2  = (const float*)d_in[12];
  const float* be2 = (const float*)d_in[13];
  const float* W3  = (const float*)d_in[14];
  const float* b3  = (const float*)d_in[15];
  const float* g3  = (const float*)d_in[16];
  const float* be3 = (const float*)d_in[17];
  const float* expW  = (const float*)d_in[24];
  const float* expb  = (const float*)d_in[25];
  const float* expg  = (const float*)d_in[26];
  const float* expbe = (const float*)d_in[27];
  const float* dww  = (const float*)d_in[28];
  const float* dwg  = (const float*)d_in[30];
  const float* dwbe = (const float*)d_in[31];
  const float* pwW  = (const float*)d_in[32];
  const float* pwb  = (const float*)d_in[33];
  const float* pwg  = (const float*)d_in[34];
  const float* pwbe = (const float*)d_in[35];
  const float* cg   = (const float*)d_in[36];
  const float* cbe  = (const float*)d_in[37];
  const float* projW  = (const float*)d_in[38];
  const float* projb  = (const float*)d_in[39];
  const float* projg  = (const float*)d_in[40];
  const float* projbe = (const float*)d_in[41];
  float* out = (float*)d_out;

  const float fNE = (float)NE, fNM = (float)NM;

  prep_weights<<<2624, 256, 0, stream>>>(W1, W2, W3, expW, pwW, projW);
  prep_pos<<<(NP + 255)/256, 256, 0, stream>>>(pos, batch, refl, sf);
  tail_out<<<(NM + 255)/256, 256, 0, stream>>>(pos, batch, refl, sf, idx, out);
  zero_stats<<<1, 512, 0, stream>>>();

  k1_edge<<<NE/128, 256, 0, stream>>>(x, esrc, idx, b1, b2);          // stats(pre2)
  param_bn<<<1, 512, 0, stream>>>(g2, be2, fNE, 64);
  k2_edge<<<NE/128, 256, 0, stream>>>(b3);                            // stats(pre3) + max/min
  param_bn<<<1, 512, 0, stream>>>(g3, be3, fNE, 128);
  k3_agg<<<NM*128/1024, 256, 0, stream>>>();

  // t1 = agg @ expW + expb
  gemm_mfma<1, 3, 2, false, false, true><<<dim3(469, 4), 256, 0, stream>>>(expb, NM, 512, 128);
  param_bn<<<1, 512, 0, stream>>>(expg, expbe, fNM, 512);
  ew_stats<2, 2><<<512, 256, 0, stream>>>(NM);                        // e = relu(bn(t1))
  param_dw<<<1, 512, 0, stream>>>(dww, dwg, dwbe, fNM, 512);
  // p0 = relu(bn_dw0(e)) @ pw0 + pwb0
  gemm_mfma<2, 4, 3, true, true, true><<<dim3(469, 4), 256, 0, stream>>>(pwb, NM, 512, 512);
  param_bn<<<1, 512, 0, stream>>>(pwg, pwbe, fNM, 512);
  ew_stats<3, 3><<<512, 256, 0, stream>>>(NM);                        // v0
  param_bn<<<1, 512, 0, stream>>>(cg, cbe, fNM, 512);
  ew_stats<3, 3><<<512, 256, 0, stream>>>(NM);                        // cmid
  param_dw<<<1, 512, 0, stream>>>(dww + 512, dwg + 512, dwbe + 512, fNM, 512);
  // p1
  gemm_mfma<3, 5, 2, true, true, true><<<dim3(469, 4), 256, 0, stream>>>(pwb + 512, NM, 512, 512);
  param_bn<<<1, 512, 0, stream>>>(pwg + 512, pwbe + 512, fNM, 512);
  ew_stats<2, 2><<<512, 256, 0, stream>>>(NM);                        // v1
  param_bn<<<1, 512, 0, stream>>>(cg + 512, cbe + 512, fNM, 512);
  // o = bn_c1(v1) @ projW + projb  (f32 out)
  gemm_mfma<2, 6, 0, true, false, false><<<dim3(469, 1), 256, 0, stream>>>(projb, NM, 128, 512);
  param_bn<<<1, 512, 0, stream>>>(projg, projbe, fNM, 128);
  final_out<<<NM*128/1024, 256, 0, stream>>>(out);
}

// Round 3
// 887.352 us; speedup vs baseline: 3.3404x; 1.0703x over previous
//
#include <hip/hip_runtime.h>
#include <hip/hip_bf16.h>
#include <cstdint>

#define DEV_INLINE __device__ __forceinline__

typedef unsigned short u16;
typedef unsigned int   u32;
typedef short bf16x8 __attribute__((ext_vector_type(8)));
typedef float f32x4  __attribute__((ext_vector_type(4)));

constexpr int NP = 120000, NB = 8, NM = 60000, KNN = 16;
constexpr int NE = NM * KNN;          // 960000
constexpr float EPS = 1e-5f;

constexpr size_t O_POS   = (size_t)NM * 128;
constexpr size_t O_BATCH = O_POS + (size_t)NM * 3;
constexpr size_t O_REFL  = O_BATCH + NM;
constexpr size_t O_SF    = O_REFL + NM;

// ---------------- device-global buffers -------------------------------------
__device__ float  g_pos_s[(size_t)NP * 4];
// pre2 in MFMA fragment-tile layout: tile t (16 rows) -> [ks(2)][lane(64)][j(8)]
// elem (row = t*16 + (lane&15), k = ks*32 + (lane>>4)*8 + j)
__device__ u16    g_pre2[(size_t)NE * 64];
__device__ u32    g_mm[(size_t)NM * 128];         // packed bf16 {lo=max, hi=min}
__device__ float  g_agg[(size_t)NM * 128];        // f32 residual
__device__ u16    g_aggbf[(size_t)NM * 128];      // bf16 GEMM input
__device__ u16    g_bufA[(size_t)NM * 512];
__device__ u16    g_bufB[(size_t)NM * 512];
__device__ float  g_obuf[(size_t)NM * 128];
__device__ float  g_sum[512], g_sqs[512], g_cfa[512], g_cfb[512];
__device__ float  g_b3adj[128], g_pbadj[128];
// transposed bf16 weights [N][K]
__device__ u16 g_w1t[64 * 64];      // K padded 36->64 (zeros)
__device__ u16 g_w2t[64 * 64];
__device__ u16 g_w3t[128 * 64];     // gets bn2-folded in place per launch
__device__ u16 g_expwt[512 * 128];
__device__ u16 g_pw0t[512 * 512];
__device__ u16 g_pw1t[512 * 512];
__device__ u16 g_projwt[128 * 512]; // gets c1-bn-folded in place per launch

template<int ID> DEV_INLINE const u16* ubufsel() {
  if constexpr (ID == 1) return g_aggbf;
  else if constexpr (ID == 2) return g_bufA;
  else return g_bufB;
}
template<int ID> DEV_INLINE u16* obufsel() {
  if constexpr (ID == 2) return g_bufA;
  else return g_bufB;
}
template<int ID> DEV_INLINE const u16* wsel() {
  if constexpr (ID == 3) return g_expwt;
  else if constexpr (ID == 4) return g_pw0t;
  else if constexpr (ID == 5) return g_pw1t;
  else return g_projwt;
}

// ---------------- helpers ----------------------------------------------------
DEV_INLINE float bf2f(u16 u) { u32 x = (u32)u << 16; float f; __builtin_memcpy(&f, &x, 4); return f; }
DEV_INLINE u16 f2bf(float f) {
  u32 x; __builtin_memcpy(&x, &f, 4);
  return (u16)((x + 0x7FFFu + ((x >> 16) & 1u)) >> 16);
}
DEV_INLINE u32 pack2(float a, float b) { return (u32)f2bf(a) | ((u32)f2bf(b) << 16); }

// affine (+optional relu) on 8 packed bf16, channels kbase..kbase+7
DEV_INLINE uint4 affine8(uint4 v, int kbase, bool relu) {
  u32 u[4] = {v.x, v.y, v.z, v.w};
  u32 r[4];
#pragma unroll
  for (int q = 0; q < 4; q++) {
    float lo = bf2f((u16)(u[q] & 0xFFFFu));
    float hi = bf2f((u16)(u[q] >> 16));
    lo = fmaf(g_cfa[kbase + 2*q],     lo, g_cfb[kbase + 2*q]);
    hi = fmaf(g_cfa[kbase + 2*q + 1], hi, g_cfb[kbase + 2*q + 1]);
    if (relu) { lo = fmaxf(lo, 0.f); hi = fmaxf(hi, 0.f); }
    r[q] = (u32)f2bf(lo) | ((u32)f2bf(hi) << 16);
  }
  return make_uint4(r[0], r[1], r[2], r[3]);
}

// ---------------- tiny kernels ----------------------------------------------
__global__ void prep_pos(const float* __restrict__ pos, const int* __restrict__ batch,
                         const float* __restrict__ refl, const float* __restrict__ sf) {
  int i = blockIdx.x * blockDim.x + threadIdx.x;
  if (i >= NP) return;
  float s = sf[batch[i]];
  float4 v;
  v.x = pos[(size_t)i*3+0] / s;
  v.y = pos[(size_t)i*3+1] / s;
  v.z = pos[(size_t)i*3+2] / s;
  v.w = refl[i];   // gate == 1 exactly
  *reinterpret_cast<float4*>(g_pos_s + (size_t)i*4) = v;
}

__global__ void tail_out(const float* __restrict__ pos, const int* __restrict__ batch,
                         const float* __restrict__ refl, const float* __restrict__ sf,
                         const int* __restrict__ idx, float* __restrict__ out) {
  int i = blockIdx.x * blockDim.x + threadIdx.x;
  if (i < NM) {
    int p = idx[i];
    out[O_POS + (size_t)i*3+0] = pos[(size_t)p*3+0];
    out[O_POS + (size_t)i*3+1] = pos[(size_t)p*3+1];
    out[O_POS + (size_t)i*3+2] = pos[(size_t)p*3+2];
    out[O_BATCH + i] = (float)batch[p];
    out[O_REFL  + i] = refl[p];
  }
  if (i < NB) out[O_SF + i] = sf[i];
}

__global__ void zero_stats() {
  int t = threadIdx.x;
  g_sum[t] = 0.f; g_sqs[t] = 0.f;
}

// transpose + bf16-convert all weights (one kernel)
__global__ void prep_weights(const float* __restrict__ W1, const float* __restrict__ W2,
                             const float* __restrict__ W3, const float* __restrict__ expW,
                             const float* __restrict__ pwW, const float* __restrict__ projW) {
  int i = blockIdx.x * 256 + threadIdx.x;
  const int s0 = 4096, s1 = 4096, s2 = 8192, s3 = 65536, s4 = 262144, s5 = 262144, s6 = 65536;
  if (i < s0) { int n = i >> 6, k = i & 63; g_w1t[i] = (k < 36) ? f2bf(W1[k*64 + n]) : (u16)0; return; }
  i -= s0;
  if (i < s1) { int n = i >> 6, k = i & 63; g_w2t[i] = f2bf(W2[k*64 + n]); return; }
  i -= s1;
  if (i < s2) { int n = i >> 6, k = i & 63; g_w3t[i] = f2bf(W3[k*128 + n]); return; }
  i -= s2;
  if (i < s3) { int n = i >> 7, k = i & 127; g_expwt[i] = f2bf(expW[k*512 + n]); return; }
  i -= s3;
  if (i < s4) { int n = i >> 9, k = i & 511; g_pw0t[i] = f2bf(pwW[k*512 + n]); return; }
  i -= s4;
  if (i < s5) { int n = i >> 9, k = i & 511; g_pw1t[i] = f2bf(pwW[262144 + k*512 + n]); return; }
  i -= s5;
  if (i < s6) { int n = i >> 9, k = i & 511; g_projwt[i] = f2bf(projW[k*128 + n]); return; }
}

// param: BN of buffer whose stats are in g_sum/g_sqs; then zero stats for next user
__global__ void param_bn(const float* __restrict__ g, const float* __restrict__ be,
                         float n, int C) {
  int c = threadIdx.x;
  if (c < C) {
    float mean = g_sum[c] / n;
    float var  = fmaxf(g_sqs[c] / n - mean * mean, 0.f);
    float a = g[c] * rsqrtf(var + EPS);
    g_cfa[c] = a;
    g_cfb[c] = be[c] - a * mean;
  }
  __syncthreads();
  g_sum[c] = 0.f; g_sqs[c] = 0.f;
}

// BN of u = w*h + b_dw given stats of h (b_dw cancels)
__global__ void param_dw(const float* __restrict__ w, const float* __restrict__ g,
                         const float* __restrict__ be, float n, int C) {
  int c = threadIdx.x;
  if (c < C) {
    float mean = g_sum[c] / n;
    float var  = fmaxf(g_sqs[c] / n - mean * mean, 0.f);
    float r = rsqrtf(w[c]*w[c]*var + EPS);
    float a = w[c] * r * g[c];
    g_cfa[c] = a;
    g_cfb[c] = be[c] - a * mean;
  }
  __syncthreads();
  g_sum[c] = 0.f; g_sqs[c] = 0.f;
}

// Fold current g_cfa/g_cfb into a [N][K] bf16 weight (in place) + bias:
// bn(A)@W == A@(diag(a)W) + (b@W);  badj[n] = bias[n] + sum_k b_k * W[k][n]
template<int SID>
__global__ void scale_fold(const float* __restrict__ bias_in, int N, int K) {
  u16* Wt = (SID == 0) ? g_w3t : g_projwt;
  float* badj = (SID == 0) ? g_b3adj : g_pbadj;
  int w = (blockIdx.x * blockDim.x + threadIdx.x) >> 6;
  int lane = threadIdx.x & 63;
  if (w >= N) return;
  float acc = 0.f;
  for (int k = lane; k < K; k += 64) {
    float wv = bf2f(Wt[(size_t)w*K + k]);
    acc = fmaf(g_cfb[k], wv, acc);
    Wt[(size_t)w*K + k] = f2bf(g_cfa[k] * wv);
  }
#pragma unroll
  for (int o = 32; o; o >>= 1) acc += __shfl_xor(acc, o, 64);
  if (lane == 0) badj[w] = bias_in[w] + acc;
}

// ---------------- K1: fused gather + MLP1 + MLP2 (128 edges/block) ----------
// single aliased LDS tile (msg -> h1 -> pre2) => 37.4 KB => 4 blocks/CU
__launch_bounds__(256)
__global__ void k1_edge(const float* __restrict__ x, const int* __restrict__ esrc,
                        const int* __restrict__ idx,
                        const float* __restrict__ b1, const float* __restrict__ b2) {
  __shared__ u16 sBuf[128][72];
  __shared__ u16 sW1[64][72];
  __shared__ u16 sW2[64][72];
  __shared__ float ssum[64], ssqs[64];
  const int tid = threadIdx.x;
  const int e0 = blockIdx.x * 128;
  if (tid < 64) { ssum[tid] = 0.f; ssqs[tid] = 0.f; }
  // stage weights
  {
    int row = tid >> 2, seg = tid & 3;
    const uint4* p1 = reinterpret_cast<const uint4*>(g_w1t + row*64 + seg*16);
    const uint4* p2 = reinterpret_cast<const uint4*>(g_w2t + row*64 + seg*16);
    uint4 a0 = p1[0], a1 = p1[1], c0 = p2[0], c1 = p2[1];
    *reinterpret_cast<uint4*>(&sW1[row][seg*16])   = a0;
    *reinterpret_cast<uint4*>(&sW1[row][seg*16+8]) = a1;
    *reinterpret_cast<uint4*>(&sW2[row][seg*16])   = c0;
    *reinterpret_cast<uint4*>(&sW2[row][seg*16+8]) = c1;
  }
  // gather msg tile
  {
    int e = tid >> 1, half = tid & 1;
    int ge = e0 + e;
    int s = esrc[ge];
    const float4* xs = reinterpret_cast<const float4*>(x + (size_t)s * 32);
    if (half == 0) {
      float4 v0 = xs[0], v1 = xs[1], v2 = xs[2], v3 = xs[3];
      uint4 u0 = make_uint4(pack2(v0.x,v0.y), pack2(v0.z,v0.w), pack2(v1.x,v1.y), pack2(v1.z,v1.w));
      uint4 u1 = make_uint4(pack2(v2.x,v2.y), pack2(v2.z,v2.w), pack2(v3.x,v3.y), pack2(v3.z,v3.w));
      *reinterpret_cast<uint4*>(&sBuf[e][0]) = u0;
      *reinterpret_cast<uint4*>(&sBuf[e][8]) = u1;
    } else {
      float4 v0 = xs[4], v1 = xs[5], v2 = xs[6], v3 = xs[7];
      uint4 u0 = make_uint4(pack2(v0.x,v0.y), pack2(v0.z,v0.w), pack2(v1.x,v1.y), pack2(v1.z,v1.w));
      uint4 u1 = make_uint4(pack2(v2.x,v2.y), pack2(v2.z,v2.w), pack2(v3.x,v3.y), pack2(v3.z,v3.w));
      *reinterpret_cast<uint4*>(&sBuf[e][16]) = u0;
      *reinterpret_cast<uint4*>(&sBuf[e][24]) = u1;
      int c = idx[ge >> 4];   // edge_dst == repeat(arange(M), 16)
      float4 ps = *reinterpret_cast<const float4*>(g_pos_s + (size_t)s * 4);
      float4 pc = *reinterpret_cast<const float4*>(g_pos_s + (size_t)c * 4);
      uint4 ur = make_uint4(pack2(ps.x-pc.x, ps.y-pc.y), pack2(ps.z-pc.z, ps.w-pc.w), 0u, 0u);
      *reinterpret_cast<uint4*>(&sBuf[e][32]) = ur;
      *reinterpret_cast<uint4*>(&sBuf[e][40]) = make_uint4(0,0,0,0);
      *reinterpret_cast<uint4*>(&sBuf[e][48]) = make_uint4(0,0,0,0);
      *reinterpret_cast<uint4*>(&sBuf[e][56]) = make_uint4(0,0,0,0);
    }
  }
  __syncthreads();
  const int w = tid >> 6, lane = tid & 63, l15 = lane & 15, l4 = lane >> 4;
  // gemm1: h1 = relu(msg @ W1 + b1)   (wave: 32 rows x 64 cols)
  f32x4 acc1[2][4] = {};
#pragma unroll
  for (int ks = 0; ks < 2; ks++) {
    bf16x8 a0 = *reinterpret_cast<const bf16x8*>(&sBuf[w*32 + l15][ks*32 + l4*8]);
    bf16x8 a1 = *reinterpret_cast<const bf16x8*>(&sBuf[w*32 + 16 + l15][ks*32 + l4*8]);
#pragma unroll
    for (int fc = 0; fc < 4; fc++) {
      bf16x8 bb = *reinterpret_cast<const bf16x8*>(&sW1[fc*16 + l15][ks*32 + l4*8]);
      acc1[0][fc] = __builtin_amdgcn_mfma_f32_16x16x32_bf16(a0, bb, acc1[0][fc], 0, 0, 0);
      acc1[1][fc] = __builtin_amdgcn_mfma_f32_16x16x32_bf16(a1, bb, acc1[1][fc], 0, 0, 0);
    }
  }
  // write h into the SAME buffer (wave-local rows; reads already consumed)
#pragma unroll
  for (int fc = 0; fc < 4; fc++) {
    float bv = b1[fc*16 + l15];
#pragma unroll
    for (int fr = 0; fr < 2; fr++)
#pragma unroll
      for (int r = 0; r < 4; r++) {
        float v = fmaxf(acc1[fr][fc][r] + bv, 0.f);
        sBuf[w*32 + fr*16 + l4*4 + r][fc*16 + l15] = f2bf(v);
      }
  }
  __syncthreads();
  // gemm2: pre2 = relu(h1 @ W2 + b2)
  f32x4 acc2[2][4] = {};
#pragma unroll
  for (int ks = 0; ks < 2; ks++) {
    bf16x8 a0 = *reinterpret_cast<const bf16x8*>(&sBuf[w*32 + l15][ks*32 + l4*8]);
    bf16x8 a1 = *reinterpret_cast<const bf16x8*>(&sBuf[w*32 + 16 + l15][ks*32 + l4*8]);
#pragma unroll
    for (int fc = 0; fc < 4; fc++) {
      bf16x8 bb = *reinterpret_cast<const bf16x8*>(&sW2[fc*16 + l15][ks*32 + l4*8]);
      acc2[0][fc] = __builtin_amdgcn_mfma_f32_16x16x32_bf16(a0, bb, acc2[0][fc], 0, 0, 0);
      acc2[1][fc] = __builtin_amdgcn_mfma_f32_16x16x32_bf16(a1, bb, acc2[1][fc], 0, 0, 0);
    }
  }
  // epilogue: relu + stats + bounce into sBuf (wave-local rows)
#pragma unroll
  for (int fc = 0; fc < 4; fc++) {
    float bv = b2[fc*16 + l15];
    float s = 0.f, q = 0.f;
#pragma unroll
    for (int fr = 0; fr < 2; fr++)
#pragma unroll
      for (int r = 0; r < 4; r++) {
        float v = fmaxf(acc2[fr][fc][r] + bv, 0.f);
        s += v; q += v*v;
        sBuf[w*32 + fr*16 + l4*4 + r][fc*16 + l15] = f2bf(v);
      }
    atomicAdd(&ssum[fc*16 + l15], s);
    atomicAdd(&ssqs[fc*16 + l15], q);
  }
  __syncthreads();
  if (tid < 64) { atomicAdd(&g_sum[tid], ssum[tid]); atomicAdd(&g_sqs[tid], ssqs[tid]); }
  // store pre2 in fragment-tile layout (coalesced 16B chunks)
  {
    int row = tid >> 1, seg = tid & 1;
    size_t tbase = (size_t)(e0/16 + (row >> 4)) * 1024 + seg*512 + (size_t)(row & 15) * 8;
#pragma unroll
    for (int l4g = 0; l4g < 4; l4g++) {
      uint4 v = *reinterpret_cast<const uint4*>(&sBuf[row][seg*32 + l4g*8]);
      *reinterpret_cast<uint4*>(g_pre2 + tbase + l4g*128) = v;
    }
  }
}

// ---------------- K2: LDS-free MLP3 + stats + per-center max/min ------------
// bn2 pre-folded into g_w3t/g_b3adj; W3 fragments live in registers.
constexpr int K2_BLOCKS = 960;
__launch_bounds__(256)
__global__ void k2_edge() {
  __shared__ float ssum[128], ssqs[128];
  const int tid = threadIdx.x;
  if (tid < 128) { ssum[tid] = 0.f; ssqs[tid] = 0.f; }
  __syncthreads();
  const int lane = tid & 63, l15 = lane & 15, l4 = lane >> 4;
  const int wglobal = blockIdx.x * 4 + (tid >> 6);
  const int WSTRIDE = K2_BLOCKS * 4;
  bf16x8 w3f[2][8];
#pragma unroll
  for (int ks = 0; ks < 2; ks++)
#pragma unroll
    for (int fc = 0; fc < 8; fc++)
      w3f[ks][fc] = *reinterpret_cast<const bf16x8*>(g_w3t + (size_t)(fc*16 + l15)*64 + ks*32 + l4*8);
  float bv[8];
#pragma unroll
  for (int fc = 0; fc < 8; fc++) bv[fc] = g_b3adj[fc*16 + l15];
  float s[8] = {}, q[8] = {};
  int t = wglobal;
  uint4 an0 = make_uint4(0,0,0,0), an1 = an0;
  if (t < NM) {
    const uint4* p = reinterpret_cast<const uint4*>(g_pre2 + (size_t)t*1024 + lane*8);
    an0 = p[0]; an1 = p[64];
  }
  for (; t < NM; t += WSTRIDE) {
    uint4 a0 = an0, a1 = an1;
    int tn = t + WSTRIDE;
    if (tn < NM) {
      const uint4* p = reinterpret_cast<const uint4*>(g_pre2 + (size_t)tn*1024 + lane*8);
      an0 = p[0]; an1 = p[64];
    }
    bf16x8 af0 = __builtin_bit_cast(bf16x8, a0);
    bf16x8 af1 = __builtin_bit_cast(bf16x8, a1);
    f32x4 acc[8] = {};
#pragma unroll
    for (int fc = 0; fc < 8; fc++) {
      acc[fc] = __builtin_amdgcn_mfma_f32_16x16x32_bf16(af0, w3f[0][fc], acc[fc], 0, 0, 0);
      acc[fc] = __builtin_amdgcn_mfma_f32_16x16x32_bf16(af1, w3f[1][fc], acc[fc], 0, 0, 0);
    }
    u32 rbase = (u32)t * 128u;
#pragma unroll
    for (int fc = 0; fc < 8; fc++) {
      float v0 = fmaxf(acc[fc][0] + bv[fc], 0.f);
      float v1 = fmaxf(acc[fc][1] + bv[fc], 0.f);
      float v2 = fmaxf(acc[fc][2] + bv[fc], 0.f);
      float v3 = fmaxf(acc[fc][3] + bv[fc], 0.f);
      s[fc] += (v0 + v1) + (v2 + v3);
      q[fc] += (v0*v0 + v1*v1) + (v2*v2 + v3*v3);
      float mx = fmaxf(fmaxf(v0, v1), fmaxf(v2, v3));
      float mn = fminf(fminf(v0, v1), fminf(v2, v3));
      mx = fmaxf(mx, __shfl_xor(mx, 16, 64)); mx = fmaxf(mx, __shfl_xor(mx, 32, 64));
      mn = fminf(mn, __shfl_xor(mn, 16, 64)); mn = fminf(mn, __shfl_xor(mn, 32, 64));
      if (l4 == (fc & 3))
        g_mm[rbase + fc*16 + l15] = (u32)f2bf(mx) | ((u32)f2bf(mn) << 16);
    }
  }
#pragma unroll
  for (int fc = 0; fc < 8; fc++) {
    float sv = s[fc], qv = q[fc];
    sv += __shfl_xor(sv, 16, 64); sv += __shfl_xor(sv, 32, 64);
    qv += __shfl_xor(qv, 16, 64); qv += __shfl_xor(qv, 32, 64);
    if (l4 == 0) { atomicAdd(&ssum[fc*16 + l15], sv); atomicAdd(&ssqs[fc*16 + l15], qv); }
  }
  __syncthreads();
  if (tid < 128) { atomicAdd(&g_sum[tid], ssum[tid]); atomicAdd(&g_sqs[tid], ssqs[tid]); }
}

// K3: agg = bn3-affine of packed max/min (sign-select); write f32 residual + bf16
__global__ void k3_agg() {
  int i4 = (blockIdx.x * 256 + threadIdx.x) * 4;
  if (i4 >= NM * 128) return;
  int c = i4 & 127;
  uint4 mm = *reinterpret_cast<const uint4*>(g_mm + i4);
  float4 a = *reinterpret_cast<const float4*>(g_cfa + c);
  float4 b = *reinterpret_cast<const float4*>(g_cfb + c);
  u32 u[4] = {mm.x, mm.y, mm.z, mm.w};
  float av[4] = {a.x, a.y, a.z, a.w};
  float bb[4] = {b.x, b.y, b.z, b.w};
  float4 r;
  float* rr = &r.x;
#pragma unroll
  for (int j = 0; j < 4; j++) {
    float mx = bf2f((u16)(u[j] & 0xFFFFu));
    float mn = bf2f((u16)(u[j] >> 16));
    rr[j] = av[j] > 0.f ? fmaf(av[j], mx, bb[j]) : fmaf(av[j], mn, bb[j]);
  }
  *reinterpret_cast<float4*>(g_agg + i4) = r;
  uint2 pk; pk.x = pack2(r.x, r.y); pk.y = pack2(r.z, r.w);
  *reinterpret_cast<uint2*>(g_aggbf + i4) = pk;
}

// ---------------- MFMA GEMM: Out[M,N] = PRO(A[M,K]) @ Bt[N,K]^T + bias ------
// 128x128 tile, 256 thr (4 waves 2x2), BK=32, fused column-stats epilogue.
template<int AID, int WID, int OID, bool PRO_AFF, bool PRO_RELU, bool OUT_BF16, bool BIAS_DEV>
__launch_bounds__(256)
__global__ void gemm_mfma(const float* __restrict__ bias, int Mrows, int Ncols, int Kdim) {
  const u16* __restrict__ A  = ubufsel<AID>();
  const u16* __restrict__ Bt = wsel<WID>();
  __shared__ u16 As[128][40];
  __shared__ u16 Bs[128][40];
  __shared__ float ssum[128], ssqs[128];
  const int tid = threadIdx.x;
  const int m0 = blockIdx.x * 128, n0 = blockIdx.y * 128;
  if (tid < 128) { ssum[tid] = 0.f; ssqs[tid] = 0.f; }
  const int wave = tid >> 6, lane = tid & 63, l15 = lane & 15, l4 = lane >> 4;
  const int wr = wave >> 1, wc = wave & 1;
  const int srow = tid >> 1, sseg = tid & 1;
  const int gr = m0 + srow;
  const bool aval = gr < Mrows;
  f32x4 acc[4][4] = {};
  for (int k0 = 0; k0 < Kdim; k0 += 32) {
    uint4 va0 = make_uint4(0,0,0,0), va1 = va0;
    if (aval) {
      const uint4* p = reinterpret_cast<const uint4*>(A + (size_t)gr*Kdim + k0 + sseg*16);
      va0 = p[0]; va1 = p[1];
    }
    if (PRO_AFF) {
      va0 = affine8(va0, k0 + sseg*16,     PRO_RELU);
      va1 = affine8(va1, k0 + sseg*16 + 8, PRO_RELU);
    }
    const uint4* pb = reinterpret_cast<const uint4*>(Bt + (size_t)(n0 + srow)*Kdim + k0 + sseg*16);
    uint4 vb0 = pb[0], vb1 = pb[1];
    __syncthreads();   // protect previous iteration's fragment reads
    *reinterpret_cast<uint4*>(&As[srow][sseg*16])     = va0;
    *reinterpret_cast<uint4*>(&As[srow][sseg*16 + 8]) = va1;
    *reinterpret_cast<uint4*>(&Bs[srow][sseg*16])     = vb0;
    *reinterpret_cast<uint4*>(&Bs[srow][sseg*16 + 8]) = vb1;
    __syncthreads();
    bf16x8 af[4], bf[4];
#pragma unroll
    for (int fr = 0; fr < 4; fr++)
      af[fr] = *reinterpret_cast<const bf16x8*>(&As[wr*64 + fr*16 + l15][l4*8]);
#pragma unroll
    for (int fc = 0; fc < 4; fc++)
      bf[fc] = *reinterpret_cast<const bf16x8*>(&Bs[wc*64 + fc*16 + l15][l4*8]);
#pragma unroll
    for (int fr = 0; fr < 4; fr++)
#pragma unroll
      for (int fc = 0; fc < 4; fc++)
        acc[fr][fc] = __builtin_amdgcn_mfma_f32_16x16x32_bf16(af[fr], bf[fc], acc[fr][fc], 0, 0, 0);
  }
  const int orow = m0 + wr*64 + l4*4;
#pragma unroll
  for (int fc = 0; fc < 4; fc++) {
    int col = n0 + wc*64 + fc*16 + l15;
    float bvv = BIAS_DEV ? g_pbadj[col] : bias[col];
    float s = 0.f, q = 0.f;
#pragma unroll
    for (int fr = 0; fr < 4; fr++)
#pragma unroll
      for (int r = 0; r < 4; r++) {
        int row = orow + fr*16 + r;
        if (row < Mrows) {
          float v = acc[fr][fc][r] + bvv;
          s += v; q += v*v;
          if (OUT_BF16) obufsel<OID>()[(size_t)row*Ncols + col] = f2bf(v);
          else          g_obuf[(size_t)row*Ncols + col] = v;
        }
      }
    atomicAdd(&ssum[wc*64 + fc*16 + l15], s);
    atomicAdd(&ssqs[wc*64 + fc*16 + l15], q);
  }
  __syncthreads();
  if (tid < 128) { atomicAdd(&g_sum[n0 + tid], ssum[tid]); atomicAdd(&g_sqs[n0 + tid], ssqs[tid]); }
}

// ---------------- EW: y = relu(a*x+b) (bf16->bf16) + fused stats -------------
template<int INID, int OUTID>
__launch_bounds__(256)
__global__ void ew_stats(int rows) {
  const u16* __restrict__ X = ubufsel<INID>();
  u16* __restrict__ Y = obufsel<OUTID>();
  __shared__ float ssum[512], ssqs[512];
  const int tid = threadIdx.x;
  ssum[tid] = 0.f; ssum[tid+256] = 0.f; ssqs[tid] = 0.f; ssqs[tid+256] = 0.f;
  __syncthreads();
  const int c0 = (tid & 63) * 8;
  const int rl = tid >> 6;
  float a[8], b[8];
#pragma unroll
  for (int j = 0; j < 8; j++) { a[j] = g_cfa[c0+j]; b[j] = g_cfb[c0+j]; }
  float s[8] = {}, q[8] = {};
  for (int r = blockIdx.x*4 + rl; r < rows; r += gridDim.x*4) {
    uint4 v = *reinterpret_cast<const uint4*>(X + (size_t)r*512 + c0);
    u32 u[4] = {v.x, v.y, v.z, v.w}, o[4];
#pragma unroll
    for (int t = 0; t < 4; t++) {
      float lo = bf2f((u16)(u[t] & 0xFFFFu));
      float hi = bf2f((u16)(u[t] >> 16));
      lo = fmaxf(fmaf(a[2*t],   lo, b[2*t]),   0.f);
      hi = fmaxf(fmaf(a[2*t+1], hi, b[2*t+1]), 0.f);
      s[2*t] += lo; q[2*t] += lo*lo; s[2*t+1] += hi; q[2*t+1] += hi*hi;
      o[t] = (u32)f2bf(lo) | ((u32)f2bf(hi) << 16);
    }
    *reinterpret_cast<uint4*>(Y + (size_t)r*512 + c0) = make_uint4(o[0], o[1], o[2], o[3]);
  }
#pragma unroll
  for (int j = 0; j < 8; j++) { atomicAdd(&ssum[c0+j], s[j]); atomicAdd(&ssqs[c0+j], q[j]); }
  __syncthreads();
  atomicAdd(&g_sum[tid],     ssum[tid]);     atomicAdd(&g_sqs[tid],     ssqs[tid]);
  atomicAdd(&g_sum[tid+256], ssum[tid+256]); atomicAdd(&g_sqs[tid+256], ssqs[tid+256]);
}

__global__ void final_out(float* __restrict__ out) {
  int i4 = (blockIdx.x * 256 + threadIdx.x) * 4;
  if (i4 >= NM * 128) return;
  int c = i4 & 127;
  float4 o  = *reinterpret_cast<const float4*>(g_obuf + i4);
  float4 ag = *reinterpret_cast<const float4*>(g_agg + i4);
  float4 a  = *reinterpret_cast<const float4*>(g_cfa + c);
  float4 b  = *reinterpret_cast<const float4*>(g_cfb + c);
  float4 r;
  r.x = fmaxf(fmaf(a.x, o.x, b.x) + ag.x, 0.f);
  r.y = fmaxf(fmaf(a.y, o.y, b.y) + ag.y, 0.f);
  r.z = fmaxf(fmaf(a.z, o.z, b.z) + ag.z, 0.f);
  r.w = fmaxf(fmaf(a.w, o.w, b.w) + ag.w, 0.f);
  *reinterpret_cast<float4*>(out + i4) = r;
}

// ---------------- host launch ------------------------------------------------
extern "C" void kernel_launch(void* const* d_in, const int* in_sizes, int n_in,
                              void* d_out, int out_size, void* d_ws, size_t ws_size,
                              hipStream_t stream) {
  const float* x     = (const float*)d_in[0];
  const float* pos   = (const float*)d_in[1];
  const int*   batch = (const int*)  d_in[2];
  const float* refl  = (const float*)d_in[3];
  const float* sf    = (const float*)d_in[4];
  const int*   idx   = (const int*)  d_in[5];
  const int*   esrc  = (const int*)  d_in[6];
  const float* W1  = (const float*)d_in[8];
  const float* b1  = (const float*)d_in[9];
  const float* W2  = (const float*)d_in[10];
  const float* b2  = (const float*)d_in[11];
  const float* g2  = (const float*)d_in[12];
  const float* be2 = (const float*)d_in[13];
  const float* W3  = (const float*)d_in[14];
  const float* b3  = (const float*)d_in[15];
  const float* g3  = (const float*)d_in[16];
  const float* be3 = (const float*)d_in[17];
  const float* expW  = (const float*)d_in[24];
  const float* expb  = (const float*)d_in[25];
  const float* expg  = (const float*)d_in[26];
  const float* expbe = (const float*)d_in[27];
  const float* dww  = (const float*)d_in[28];
  const float* dwg  = (const float*)d_in[30];
  const float* dwbe = (const float*)d_in[31];
  const float* pwW  = (const float*)d_in[32];
  const float* pwb  = (const float*)d_in[33];
  const float* pwg  = (const float*)d_in[34];
  const float* pwbe = (const float*)d_in[35];
  const float* cg   = (const float*)d_in[36];
  const float* cbe  = (const float*)d_in[37];
  const float* projW  = (const float*)d_in[38];
  const float* projb  = (const float*)d_in[39];
  const float* projg  = (const float*)d_in[40];
  const float* projbe = (const float*)d_in[41];
  float* out = (float*)d_out;

  const float fNE = (float)NE, fNM = (float)NM;

  prep_weights<<<2624, 256, 0, stream>>>(W1, W2, W3, expW, pwW, projW);
  prep_pos<<<(NP + 255)/256, 256, 0, stream>>>(pos, batch, refl, sf);
  tail_out<<<(NM + 255)/256, 256, 0, stream>>>(pos, batch, refl, sf, idx, out);
  zero_stats<<<1, 512, 0, stream>>>();

  k1_edge<<<NE/128, 256, 0, stream>>>(x, esrc, idx, b1, b2);          // stats(pre2)
  param_bn<<<1, 512, 0, stream>>>(g2, be2, fNE, 64);
  scale_fold<0><<<32, 256, 0, stream>>>(b3, 128, 64);                 // fold bn2 into W3/b3
  k2_edge<<<K2_BLOCKS, 256, 0, stream>>>();                           // stats(pre3) + max/min
  param_bn<<<1, 512, 0, stream>>>(g3, be3, fNE, 128);
  k3_agg<<<NM*128/1024, 256, 0, stream>>>();

  // t1 = agg @ expW + expb
  gemm_mfma<1, 3, 2, false, false, true, false><<<dim3(469, 4), 256, 0, stream>>>(expb, NM, 512, 128);
  param_bn<<<1, 512, 0, stream>>>(expg, expbe, fNM, 512);
  ew_stats<2, 2><<<512, 256, 0, stream>>>(NM);                        // e = relu(bn(t1))
  param_dw<<<1, 512, 0, stream>>>(dww, dwg, dwbe, fNM, 512);
  // p0 = relu(bn_dw0(e)) @ pw0 + pwb0
  gemm_mfma<2, 4, 3, true, true, true, false><<<dim3(469, 4), 256, 0, stream>>>(pwb, NM, 512, 512);
  param_bn<<<1, 512, 0, stream>>>(pwg, pwbe, fNM, 512);
  ew_stats<3, 3><<<512, 256, 0, stream>>>(NM);                        // v0
  param_bn<<<1, 512, 0, stream>>>(cg, cbe, fNM, 512);
  ew_stats<3, 3><<<512, 256, 0, stream>>>(NM);                        // cmid
  param_dw<<<1, 512, 0, stream>>>(dww + 512, dwg + 512, dwbe + 512, fNM, 512);
  // p1
  gemm_mfma<3, 5, 2, true, true, true, false><<<dim3(469, 4), 256, 0, stream>>>(pwb + 512, NM, 512, 512);
  param_bn<<<1, 512, 0, stream>>>(pwg + 512, pwbe + 512, fNM, 512);
  ew_stats<2, 2><<<512, 256, 0, stream>>>(NM);                        // v1
  param_bn<<<1, 512, 0, stream>>>(cg + 512, cbe + 512, fNM, 512);
  scale_fold<1><<<32, 256, 0, stream>>>(projb, 128, 512);             // fold c1-bn into projW/projb
  // o = v1 @ projW' + pbadj  (f32 out, no prologue)
  gemm_mfma<2, 6, 0, false, false, false, true><<<dim3(469, 1), 256, 0, stream>>>(projb, NM, 128, 512);
  param_bn<<<1, 512, 0, stream>>>(projg, projbe, fNM, 128);
  final_out<<<NM*128/1024, 256, 0, stream>>>(out);
}

// Round 4
// 812.171 us; speedup vs baseline: 3.6496x; 1.0926x over previous
//
#include <hip/hip_runtime.h>
#include <hip/hip_bf16.h>
#include <cstdint>

#define DEV_INLINE __device__ __forceinline__

typedef unsigned short u16;
typedef unsigned int   u32;
typedef short bf16x8 __attribute__((ext_vector_type(8)));
typedef float f32x4  __attribute__((ext_vector_type(4)));

constexpr int NP = 120000, NB = 8, NM = 60000, KNN = 16;
constexpr int NE = NM * KNN;          // 960000
constexpr float EPS = 1e-5f;

constexpr size_t O_POS   = (size_t)NM * 128;
constexpr size_t O_BATCH = O_POS + (size_t)NM * 3;
constexpr size_t O_REFL  = O_BATCH + NM;
constexpr size_t O_SF    = O_REFL + NM;

// ---------------- device-global buffers -------------------------------------
__device__ float  g_pos_s[(size_t)NP * 4];
__device__ u16    g_xbf[(size_t)NP * 32];         // x in bf16
// pre2 in MFMA fragment-tile layout: tile t (16 rows=edges of center t):
// g_pre2[t*1024 + ks*512 + lane*8 + j] = pre2[t*16+(lane&15)][ks*32+(lane>>4)*8+j]
__device__ u16    g_pre2[(size_t)NE * 64];
__device__ u32    g_mm[(size_t)NM * 128];         // packed bf16 {lo=max, hi=min}
__device__ float  g_agg[(size_t)NM * 128];        // f32 residual
__device__ u16    g_aggbf[(size_t)NM * 128];      // bf16 GEMM input
__device__ u16    g_bufA[(size_t)NM * 512];
__device__ u16    g_bufB[(size_t)NM * 512];
__device__ float  g_obuf[(size_t)NM * 128];
__device__ float  g_sum[512], g_sqs[512], g_cfa[512], g_cfb[512];
__device__ float  g_b3adj[128], g_pbadj[128];
// transposed bf16 weights [N][K]
__device__ u16 g_w1t[64 * 64];      // K padded 36->64 (zeros)
__device__ u16 g_w2t[64 * 64];
__device__ u16 g_w3t[128 * 64];     // gets bn2-folded in place per launch
__device__ u16 g_expwt[512 * 128];
__device__ u16 g_pw0t[512 * 512];
__device__ u16 g_pw1t[512 * 512];
__device__ u16 g_projwt[128 * 512]; // gets c1-bn-folded in place per launch

template<int ID> DEV_INLINE const u16* ubufsel() {
  if constexpr (ID == 1) return g_aggbf;
  else if constexpr (ID == 2) return g_bufA;
  else return g_bufB;
}
template<int ID> DEV_INLINE u16* obufsel() {
  if constexpr (ID == 2) return g_bufA;
  else return g_bufB;
}
template<int ID> DEV_INLINE const u16* wsel() {
  if constexpr (ID == 3) return g_expwt;
  else if constexpr (ID == 4) return g_pw0t;
  else if constexpr (ID == 5) return g_pw1t;
  else return g_projwt;
}

// ---------------- helpers ----------------------------------------------------
DEV_INLINE float bf2f(u16 u) { u32 x = (u32)u << 16; float f; __builtin_memcpy(&f, &x, 4); return f; }
DEV_INLINE u16 f2bf(float f) {
  u32 x; __builtin_memcpy(&x, &f, 4);
  return (u16)((x + 0x7FFFu + ((x >> 16) & 1u)) >> 16);
}
DEV_INLINE u32 pack2(float a, float b) { return (u32)f2bf(a) | ((u32)f2bf(b) << 16); }

// affine (+optional relu) on 8 packed bf16, channels kbase..kbase+7
DEV_INLINE uint4 affine8(uint4 v, int kbase, bool relu) {
  u32 u[4] = {v.x, v.y, v.z, v.w};
  u32 r[4];
#pragma unroll
  for (int q = 0; q < 4; q++) {
    float lo = bf2f((u16)(u[q] & 0xFFFFu));
    float hi = bf2f((u16)(u[q] >> 16));
    lo = fmaf(g_cfa[kbase + 2*q],     lo, g_cfb[kbase + 2*q]);
    hi = fmaf(g_cfa[kbase + 2*q + 1], hi, g_cfb[kbase + 2*q + 1]);
    if (relu) { lo = fmaxf(lo, 0.f); hi = fmaxf(hi, 0.f); }
    r[q] = (u32)f2bf(lo) | ((u32)f2bf(hi) << 16);
  }
  return make_uint4(r[0], r[1], r[2], r[3]);
}

// ---------------- tiny kernels ----------------------------------------------
__global__ void prep_pos_x(const float* __restrict__ pos, const int* __restrict__ batch,
                           const float* __restrict__ refl, const float* __restrict__ sf,
                           const float* __restrict__ x) {
  int i = blockIdx.x * blockDim.x + threadIdx.x;
  if (i >= NP) return;
  float s = sf[batch[i]];
  float4 v;
  v.x = pos[(size_t)i*3+0] / s;
  v.y = pos[(size_t)i*3+1] / s;
  v.z = pos[(size_t)i*3+2] / s;
  v.w = refl[i];   // gate == 1 exactly
  *reinterpret_cast<float4*>(g_pos_s + (size_t)i*4) = v;
  const float4* xr = reinterpret_cast<const float4*>(x + (size_t)i*32);
#pragma unroll
  for (int q = 0; q < 4; q++) {
    float4 a = xr[q*2], b = xr[q*2+1];
    uint4 u = make_uint4(pack2(a.x,a.y), pack2(a.z,a.w), pack2(b.x,b.y), pack2(b.z,b.w));
    *reinterpret_cast<uint4*>(g_xbf + (size_t)i*32 + q*8) = u;
  }
}

__global__ void tail_out(const float* __restrict__ pos, const int* __restrict__ batch,
                         const float* __restrict__ refl, const float* __restrict__ sf,
                         const int* __restrict__ idx, float* __restrict__ out) {
  int i = blockIdx.x * blockDim.x + threadIdx.x;
  if (i < NM) {
    int p = idx[i];
    out[O_POS + (size_t)i*3+0] = pos[(size_t)p*3+0];
    out[O_POS + (size_t)i*3+1] = pos[(size_t)p*3+1];
    out[O_POS + (size_t)i*3+2] = pos[(size_t)p*3+2];
    out[O_BATCH + i] = (float)batch[p];
    out[O_REFL  + i] = refl[p];
  }
  if (i < NB) out[O_SF + i] = sf[i];
}

__global__ void zero_stats() {
  int t = threadIdx.x;
  g_sum[t] = 0.f; g_sqs[t] = 0.f;
}

// transpose + bf16-convert all weights (one kernel)
__global__ void prep_weights(const float* __restrict__ W1, const float* __restrict__ W2,
                             const float* __restrict__ W3, const float* __restrict__ expW,
                             const float* __restrict__ pwW, const float* __restrict__ projW) {
  int i = blockIdx.x * 256 + threadIdx.x;
  const int s0 = 4096, s1 = 4096, s2 = 8192, s3 = 65536, s4 = 262144, s5 = 262144, s6 = 65536;
  if (i < s0) { int n = i >> 6, k = i & 63; g_w1t[i] = (k < 36) ? f2bf(W1[k*64 + n]) : (u16)0; return; }
  i -= s0;
  if (i < s1) { int n = i >> 6, k = i & 63; g_w2t[i] = f2bf(W2[k*64 + n]); return; }
  i -= s1;
  if (i < s2) { int n = i >> 6, k = i & 63; g_w3t[i] = f2bf(W3[k*128 + n]); return; }
  i -= s2;
  if (i < s3) { int n = i >> 7, k = i & 127; g_expwt[i] = f2bf(expW[k*512 + n]); return; }
  i -= s3;
  if (i < s4) { int n = i >> 9, k = i & 511; g_pw0t[i] = f2bf(pwW[k*512 + n]); return; }
  i -= s4;
  if (i < s5) { int n = i >> 9, k = i & 511; g_pw1t[i] = f2bf(pwW[262144 + k*512 + n]); return; }
  i -= s5;
  if (i < s6) { int n = i >> 9, k = i & 511; g_projwt[i] = f2bf(projW[k*128 + n]); return; }
}

// param: BN of buffer whose stats are in g_sum/g_sqs; then zero stats for next user
__global__ void param_bn(const float* __restrict__ g, const float* __restrict__ be,
                         float n, int C) {
  int c = threadIdx.x;
  if (c < C) {
    float mean = g_sum[c] / n;
    float var  = fmaxf(g_sqs[c] / n - mean * mean, 0.f);
    float a = g[c] * rsqrtf(var + EPS);
    g_cfa[c] = a;
    g_cfb[c] = be[c] - a * mean;
  }
  __syncthreads();
  g_sum[c] = 0.f; g_sqs[c] = 0.f;
}

// BN of u = w*h + b_dw given stats of h (b_dw cancels)
__global__ void param_dw(const float* __restrict__ w, const float* __restrict__ g,
                         const float* __restrict__ be, float n, int C) {
  int c = threadIdx.x;
  if (c < C) {
    float mean = g_sum[c] / n;
    float var  = fmaxf(g_sqs[c] / n - mean * mean, 0.f);
    float r = rsqrtf(w[c]*w[c]*var + EPS);
    float a = w[c] * r * g[c];
    g_cfa[c] = a;
    g_cfb[c] = be[c] - a * mean;
  }
  __syncthreads();
  g_sum[c] = 0.f; g_sqs[c] = 0.f;
}

// Fold current g_cfa/g_cfb into a [N][K] bf16 weight (in place) + bias:
// bn(A)@W == A@(diag(a)W) + (b@W);  badj[n] = bias[n] + sum_k b_k * W[k][n]
template<int SID>
__global__ void scale_fold(const float* __restrict__ bias_in, int N, int K) {
  u16* Wt = (SID == 0) ? g_w3t : g_projwt;
  float* badj = (SID == 0) ? g_b3adj : g_pbadj;
  int w = (blockIdx.x * blockDim.x + threadIdx.x) >> 6;
  int lane = threadIdx.x & 63;
  if (w >= N) return;
  float acc = 0.f;
  for (int k = lane; k < K; k += 64) {
    float wv = bf2f(Wt[(size_t)w*K + k]);
    acc = fmaf(g_cfb[k], wv, acc);
    Wt[(size_t)w*K + k] = f2bf(g_cfa[k] * wv);
  }
#pragma unroll
  for (int o = 32; o; o >>= 1) acc += __shfl_xor(acc, o, 64);
  if (lane == 0) badj[w] = bias_in[w] + acc;
}

// ---------------- K1: wave-autonomous gather + MLP1 + MLP2 ------------------
// One wave per 16-edge tile (= one center), grid-stride, weights in registers,
// per-wave LDS bounce for the C-layout -> A-layout transposes. No in-loop
// barriers; pre2 stored directly in k2's fragment layout.
constexpr int K1_BLOCKS = 960;
__launch_bounds__(256)
__global__ void k1_edge(const int* __restrict__ esrc, const int* __restrict__ idx,
                        const float* __restrict__ b1v, const float* __restrict__ b2v) {
  __shared__ u16 sH[4][16][72];
  __shared__ float ssum[64], ssqs[64];
  const int tid = threadIdx.x;
  if (tid < 64) { ssum[tid] = 0.f; ssqs[tid] = 0.f; }
  __syncthreads();
  const int w = tid >> 6, lane = tid & 63, l15 = lane & 15, l4 = lane >> 4;
  u16 (*sh)[72] = sH[w];
  bf16x8 w1f[2][4], w2f[2][4];
#pragma unroll
  for (int ks = 0; ks < 2; ks++)
#pragma unroll
    for (int fc = 0; fc < 4; fc++) {
      w1f[ks][fc] = *reinterpret_cast<const bf16x8*>(g_w1t + (size_t)(fc*16+l15)*64 + ks*32 + l4*8);
      w2f[ks][fc] = *reinterpret_cast<const bf16x8*>(g_w2t + (size_t)(fc*16+l15)*64 + ks*32 + l4*8);
    }
  float b1r[4], b2r[4];
#pragma unroll
  for (int fc = 0; fc < 4; fc++) { b1r[fc] = b1v[fc*16+l15]; b2r[fc] = b2v[fc*16+l15]; }
  float s8[4] = {}, q8[4] = {};
  const int t0 = blockIdx.x * 4 + w;
  const int TSTRIDE = K1_BLOCKS * 4;
  // prefetch tile t0
  int   s_cur = esrc[t0*16 + l15];
  uint4 x_cur = *reinterpret_cast<const uint4*>(g_xbf + (size_t)s_cur*32 + l4*8);
  float4 ps_cur = make_float4(0.f,0.f,0.f,0.f);
  if (l4 == 0) ps_cur = *reinterpret_cast<const float4*>(g_pos_s + (size_t)s_cur*4);
  float4 pc_cur = *reinterpret_cast<const float4*>(g_pos_s + (size_t)idx[t0]*4);

  for (int t = t0; t < NM; t += TSTRIDE) {
    const int tn = t + TSTRIDE;
    int s_nx = 0; uint4 x_nx = make_uint4(0,0,0,0);
    float4 ps_nx = ps_cur, pc_nx = pc_cur;
    if (tn < NM) {
      s_nx = esrc[tn*16 + l15];
      x_nx = *reinterpret_cast<const uint4*>(g_xbf + (size_t)s_nx*32 + l4*8);
      if (l4 == 0) ps_nx = *reinterpret_cast<const float4*>(g_pos_s + (size_t)s_nx*4);
      pc_nx = *reinterpret_cast<const float4*>(g_pos_s + (size_t)idx[tn]*4);
    }
    // A-fragments: ks=0 covers x's 32 channels; ks=1 = rel (l4==0) + zero pad
    bf16x8 a0 = __builtin_bit_cast(bf16x8, x_cur);
    uint4 r4 = make_uint4(0,0,0,0);
    if (l4 == 0) {
      r4.x = pack2(ps_cur.x - pc_cur.x, ps_cur.y - pc_cur.y);
      r4.y = pack2(ps_cur.z - pc_cur.z, ps_cur.w - pc_cur.w);
    }
    bf16x8 a1 = __builtin_bit_cast(bf16x8, r4);
    // gemm1: h1 = relu(msg @ W1 + b1)
    f32x4 acc1[4] = {};
#pragma unroll
    for (int fc = 0; fc < 4; fc++) {
      acc1[fc] = __builtin_amdgcn_mfma_f32_16x16x32_bf16(a0, w1f[0][fc], acc1[fc], 0, 0, 0);
      acc1[fc] = __builtin_amdgcn_mfma_f32_16x16x32_bf16(a1, w1f[1][fc], acc1[fc], 0, 0, 0);
    }
    // bounce h1: C-layout -> A-layout (wave-local LDS, in-order pipe, no barrier)
#pragma unroll
    for (int fc = 0; fc < 4; fc++)
#pragma unroll
      for (int r = 0; r < 4; r++)
        sh[l4*4 + r][fc*16 + l15] = f2bf(fmaxf(acc1[fc][r] + b1r[fc], 0.f));
    bf16x8 h0  = *reinterpret_cast<const bf16x8*>(&sh[l15][l4*8]);
    bf16x8 h1v = *reinterpret_cast<const bf16x8*>(&sh[l15][32 + l4*8]);
    // gemm2: pre2 = relu(h1 @ W2 + b2)
    f32x4 acc2[4] = {};
#pragma unroll
    for (int fc = 0; fc < 4; fc++) {
      acc2[fc] = __builtin_amdgcn_mfma_f32_16x16x32_bf16(h0,  w2f[0][fc], acc2[fc], 0, 0, 0);
      acc2[fc] = __builtin_amdgcn_mfma_f32_16x16x32_bf16(h1v, w2f[1][fc], acc2[fc], 0, 0, 0);
    }
    // epilogue: relu + stats + bounce to A-layout + coalesced store
#pragma unroll
    for (int fc = 0; fc < 4; fc++)
#pragma unroll
      for (int r = 0; r < 4; r++) {
        float v = fmaxf(acc2[fc][r] + b2r[fc], 0.f);
        s8[fc] += v; q8[fc] += v*v;
        sh[l4*4 + r][fc*16 + l15] = f2bf(v);
      }
    uint4 p0 = *reinterpret_cast<const uint4*>(&sh[l15][l4*8]);
    uint4 p1 = *reinterpret_cast<const uint4*>(&sh[l15][32 + l4*8]);
    *reinterpret_cast<uint4*>(g_pre2 + (size_t)t*1024 + lane*8)       = p0;
    *reinterpret_cast<uint4*>(g_pre2 + (size_t)t*1024 + 512 + lane*8) = p1;
    s_cur = s_nx; x_cur = x_nx; ps_cur = ps_nx; pc_cur = pc_nx;
  }
  // stats: reduce over l4 then block-LDS then global
#pragma unroll
  for (int fc = 0; fc < 4; fc++) {
    float sv = s8[fc], qv = q8[fc];
    sv += __shfl_xor(sv, 16, 64); sv += __shfl_xor(sv, 32, 64);
    qv += __shfl_xor(qv, 16, 64); qv += __shfl_xor(qv, 32, 64);
    if (l4 == 0) { atomicAdd(&ssum[fc*16 + l15], sv); atomicAdd(&ssqs[fc*16 + l15], qv); }
  }
  __syncthreads();
  if (tid < 64) { atomicAdd(&g_sum[tid], ssum[tid]); atomicAdd(&g_sqs[tid], ssqs[tid]); }
}

// ---------------- K2: LDS-free MLP3 + stats + per-center max/min ------------
// bn2 pre-folded into g_w3t/g_b3adj; W3 fragments live in registers.
constexpr int K2_BLOCKS = 960;
__launch_bounds__(256)
__global__ void k2_edge() {
  __shared__ float ssum[128], ssqs[128];
  const int tid = threadIdx.x;
  if (tid < 128) { ssum[tid] = 0.f; ssqs[tid] = 0.f; }
  __syncthreads();
  const int lane = tid & 63, l15 = lane & 15, l4 = lane >> 4;
  const int wglobal = blockIdx.x * 4 + (tid >> 6);
  const int WSTRIDE = K2_BLOCKS * 4;
  bf16x8 w3f[2][8];
#pragma unroll
  for (int ks = 0; ks < 2; ks++)
#pragma unroll
    for (int fc = 0; fc < 8; fc++)
      w3f[ks][fc] = *reinterpret_cast<const bf16x8*>(g_w3t + (size_t)(fc*16 + l15)*64 + ks*32 + l4*8);
  float bv[8];
#pragma unroll
  for (int fc = 0; fc < 8; fc++) bv[fc] = g_b3adj[fc*16 + l15];
  float s[8] = {}, q[8] = {};
  int t = wglobal;
  uint4 an0 = make_uint4(0,0,0,0), an1 = an0;
  if (t < NM) {
    const uint4* p = reinterpret_cast<const uint4*>(g_pre2 + (size_t)t*1024 + lane*8);
    an0 = p[0]; an1 = p[64];
  }
  for (; t < NM; t += WSTRIDE) {
    uint4 a0 = an0, a1 = an1;
    int tn = t + WSTRIDE;
    if (tn < NM) {
      const uint4* p = reinterpret_cast<const uint4*>(g_pre2 + (size_t)tn*1024 + lane*8);
      an0 = p[0]; an1 = p[64];
    }
    bf16x8 af0 = __builtin_bit_cast(bf16x8, a0);
    bf16x8 af1 = __builtin_bit_cast(bf16x8, a1);
    f32x4 acc[8] = {};
#pragma unroll
    for (int fc = 0; fc < 8; fc++) {
      acc[fc] = __builtin_amdgcn_mfma_f32_16x16x32_bf16(af0, w3f[0][fc], acc[fc], 0, 0, 0);
      acc[fc] = __builtin_amdgcn_mfma_f32_16x16x32_bf16(af1, w3f[1][fc], acc[fc], 0, 0, 0);
    }
    u32 rbase = (u32)t * 128u;
#pragma unroll
    for (int fc = 0; fc < 8; fc++) {
      float v0 = fmaxf(acc[fc][0] + bv[fc], 0.f);
      float v1 = fmaxf(acc[fc][1] + bv[fc], 0.f);
      float v2 = fmaxf(acc[fc][2] + bv[fc], 0.f);
      float v3 = fmaxf(acc[fc][3] + bv[fc], 0.f);
      s[fc] += (v0 + v1) + (v2 + v3);
      q[fc] += (v0*v0 + v1*v1) + (v2*v2 + v3*v3);
      float mx = fmaxf(fmaxf(v0, v1), fmaxf(v2, v3));
      float mn = fminf(fminf(v0, v1), fminf(v2, v3));
      mx = fmaxf(mx, __shfl_xor(mx, 16, 64)); mx = fmaxf(mx, __shfl_xor(mx, 32, 64));
      mn = fminf(mn, __shfl_xor(mn, 16, 64)); mn = fminf(mn, __shfl_xor(mn, 32, 64));
      if (l4 == (fc & 3))
        g_mm[rbase + fc*16 + l15] = (u32)f2bf(mx) | ((u32)f2bf(mn) << 16);
    }
  }
#pragma unroll
  for (int fc = 0; fc < 8; fc++) {
    float sv = s[fc], qv = q[fc];
    sv += __shfl_xor(sv, 16, 64); sv += __shfl_xor(sv, 32, 64);
    qv += __shfl_xor(qv, 16, 64); qv += __shfl_xor(qv, 32, 64);
    if (l4 == 0) { atomicAdd(&ssum[fc*16 + l15], sv); atomicAdd(&ssqs[fc*16 + l15], qv); }
  }
  __syncthreads();
  if (tid < 128) { atomicAdd(&g_sum[tid], ssum[tid]); atomicAdd(&g_sqs[tid], ssqs[tid]); }
}

// K3: agg = bn3-affine of packed max/min (sign-select); write f32 residual + bf16
__global__ void k3_agg() {
  int i4 = (blockIdx.x * 256 + threadIdx.x) * 4;
  if (i4 >= NM * 128) return;
  int c = i4 & 127;
  uint4 mm = *reinterpret_cast<const uint4*>(g_mm + i4);
  float4 a = *reinterpret_cast<const float4*>(g_cfa + c);
  float4 b = *reinterpret_cast<const float4*>(g_cfb + c);
  u32 u[4] = {mm.x, mm.y, mm.z, mm.w};
  float av[4] = {a.x, a.y, a.z, a.w};
  float bb[4] = {b.x, b.y, b.z, b.w};
  float4 r;
  float* rr = &r.x;
#pragma unroll
  for (int j = 0; j < 4; j++) {
    float mx = bf2f((u16)(u[j] & 0xFFFFu));
    float mn = bf2f((u16)(u[j] >> 16));
    rr[j] = av[j] > 0.f ? fmaf(av[j], mx, bb[j]) : fmaf(av[j], mn, bb[j]);
  }
  *reinterpret_cast<float4*>(g_agg + i4) = r;
  uint2 pk; pk.x = pack2(r.x, r.y); pk.y = pack2(r.z, r.w);
  *reinterpret_cast<uint2*>(g_aggbf + i4) = pk;
}

// ---------------- MFMA GEMM: Out[M,N] = PRO(A[M,K]) @ Bt[N,K]^T + bias ------
// 128x128 tile, 256 thr (4 waves 2x2), BK=32, fused column-stats epilogue.
template<int AID, int WID, int OID, bool PRO_AFF, bool PRO_RELU, bool OUT_BF16, bool BIAS_DEV>
__launch_bounds__(256)
__global__ void gemm_mfma(const float* __restrict__ bias, int Mrows, int Ncols, int Kdim) {
  const u16* __restrict__ A  = ubufsel<AID>();
  const u16* __restrict__ Bt = wsel<WID>();
  __shared__ u16 As[128][40];
  __shared__ u16 Bs[128][40];
  __shared__ float ssum[128], ssqs[128];
  const int tid = threadIdx.x;
  const int m0 = blockIdx.x * 128, n0 = blockIdx.y * 128;
  if (tid < 128) { ssum[tid] = 0.f; ssqs[tid] = 0.f; }
  const int wave = tid >> 6, lane = tid & 63, l15 = lane & 15, l4 = lane >> 4;
  const int wr = wave >> 1, wc = wave & 1;
  const int srow = tid >> 1, sseg = tid & 1;
  const int gr = m0 + srow;
  const bool aval = gr < Mrows;
  f32x4 acc[4][4] = {};
  for (int k0 = 0; k0 < Kdim; k0 += 32) {
    uint4 va0 = make_uint4(0,0,0,0), va1 = va0;
    if (aval) {
      const uint4* p = reinterpret_cast<const uint4*>(A + (size_t)gr*Kdim + k0 + sseg*16);
      va0 = p[0]; va1 = p[1];
    }
    if (PRO_AFF) {
      va0 = affine8(va0, k0 + sseg*16,     PRO_RELU);
      va1 = affine8(va1, k0 + sseg*16 + 8, PRO_RELU);
    }
    const uint4* pb = reinterpret_cast<const uint4*>(Bt + (size_t)(n0 + srow)*Kdim + k0 + sseg*16);
    uint4 vb0 = pb[0], vb1 = pb[1];
    __syncthreads();   // protect previous iteration's fragment reads
    *reinterpret_cast<uint4*>(&As[srow][sseg*16])     = va0;
    *reinterpret_cast<uint4*>(&As[srow][sseg*16 + 8]) = va1;
    *reinterpret_cast<uint4*>(&Bs[srow][sseg*16])     = vb0;
    *reinterpret_cast<uint4*>(&Bs[srow][sseg*16 + 8]) = vb1;
    __syncthreads();
    bf16x8 af[4], bf[4];
#pragma unroll
    for (int fr = 0; fr < 4; fr++)
      af[fr] = *reinterpret_cast<const bf16x8*>(&As[wr*64 + fr*16 + l15][l4*8]);
#pragma unroll
    for (int fc = 0; fc < 4; fc++)
      bf[fc] = *reinterpret_cast<const bf16x8*>(&Bs[wc*64 + fc*16 + l15][l4*8]);
#pragma unroll
    for (int fr = 0; fr < 4; fr++)
#pragma unroll
      for (int fc = 0; fc < 4; fc++)
        acc[fr][fc] = __builtin_amdgcn_mfma_f32_16x16x32_bf16(af[fr], bf[fc], acc[fr][fc], 0, 0, 0);
  }
  const int orow = m0 + wr*64 + l4*4;
#pragma unroll
  for (int fc = 0; fc < 4; fc++) {
    int col = n0 + wc*64 + fc*16 + l15;
    float bvv = BIAS_DEV ? g_pbadj[col] : bias[col];
    float s = 0.f, q = 0.f;
#pragma unroll
    for (int fr = 0; fr < 4; fr++)
#pragma unroll
      for (int r = 0; r < 4; r++) {
        int row = orow + fr*16 + r;
        if (row < Mrows) {
          float v = acc[fr][fc][r] + bvv;
          s += v; q += v*v;
          if (OUT_BF16) obufsel<OID>()[(size_t)row*Ncols + col] = f2bf(v);
          else          g_obuf[(size_t)row*Ncols + col] = v;
        }
      }
    atomicAdd(&ssum[wc*64 + fc*16 + l15], s);
    atomicAdd(&ssqs[wc*64 + fc*16 + l15], q);
  }
  __syncthreads();
  if (tid < 128) { atomicAdd(&g_sum[n0 + tid], ssum[tid]); atomicAdd(&g_sqs[n0 + tid], ssqs[tid]); }
}

// ---------------- EW: y = relu(a*x+b) (bf16->bf16) + fused stats -------------
template<int INID, int OUTID>
__launch_bounds__(256)
__global__ void ew_stats(int rows) {
  const u16* __restrict__ X = ubufsel<INID>();
  u16* __restrict__ Y = obufsel<OUTID>();
  __shared__ float ssum[512], ssqs[512];
  const int tid = threadIdx.x;
  ssum[tid] = 0.f; ssum[tid+256] = 0.f; ssqs[tid] = 0.f; ssqs[tid+256] = 0.f;
  __syncthreads();
  const int c0 = (tid & 63) * 8;
  const int rl = tid >> 6;
  float a[8], b[8];
#pragma unroll
  for (int j = 0; j < 8; j++) { a[j] = g_cfa[c0+j]; b[j] = g_cfb[c0+j]; }
  float s[8] = {}, q[8] = {};
  for (int r = blockIdx.x*4 + rl; r < rows; r += gridDim.x*4) {
    uint4 v = *reinterpret_cast<const uint4*>(X + (size_t)r*512 + c0);
    u32 u[4] = {v.x, v.y, v.z, v.w}, o[4];
#pragma unroll
    for (int t = 0; t < 4; t++) {
      float lo = bf2f((u16)(u[t] & 0xFFFFu));
      float hi = bf2f((u16)(u[t] >> 16));
      lo = fmaxf(fmaf(a[2*t],   lo, b[2*t]),   0.f);
      hi = fmaxf(fmaf(a[2*t+1], hi, b[2*t+1]), 0.f);
      s[2*t] += lo; q[2*t] += lo*lo; s[2*t+1] += hi; q[2*t+1] += hi*hi;
      o[t] = (u32)f2bf(lo) | ((u32)f2bf(hi) << 16);
    }
    *reinterpret_cast<uint4*>(Y + (size_t)r*512 + c0) = make_uint4(o[0], o[1], o[2], o[3]);
  }
#pragma unroll
  for (int j = 0; j < 8; j++) { atomicAdd(&ssum[c0+j], s[j]); atomicAdd(&ssqs[c0+j], q[j]); }
  __syncthreads();
  atomicAdd(&g_sum[tid],     ssum[tid]);     atomicAdd(&g_sqs[tid],     ssqs[tid]);
  atomicAdd(&g_sum[tid+256], ssum[tid+256]); atomicAdd(&g_sqs[tid+256], ssqs[tid+256]);
}

__global__ void final_out(float* __restrict__ out) {
  int i4 = (blockIdx.x * 256 + threadIdx.x) * 4;
  if (i4 >= NM * 128) return;
  int c = i4 & 127;
  float4 o  = *reinterpret_cast<const float4*>(g_obuf + i4);
  float4 ag = *reinterpret_cast<const float4*>(g_agg + i4);
  float4 a  = *reinterpret_cast<const float4*>(g_cfa + c);
  float4 b  = *reinterpret_cast<const float4*>(g_cfb + c);
  float4 r;
  r.x = fmaxf(fmaf(a.x, o.x, b.x) + ag.x, 0.f);
  r.y = fmaxf(fmaf(a.y, o.y, b.y) + ag.y, 0.f);
  r.z = fmaxf(fmaf(a.z, o.z, b.z) + ag.z, 0.f);
  r.w = fmaxf(fmaf(a.w, o.w, b.w) + ag.w, 0.f);
  *reinterpret_cast<float4*>(out + i4) = r;
}

// ---------------- host launch ------------------------------------------------
extern "C" void kernel_launch(void* const* d_in, const int* in_sizes, int n_in,
                              void* d_out, int out_size, void* d_ws, size_t ws_size,
                              hipStream_t stream) {
  const float* x     = (const float*)d_in[0];
  const float* pos   = (const float*)d_in[1];
  const int*   batch = (const int*)  d_in[2];
  const float* refl  = (const float*)d_in[3];
  const float* sf    = (const float*)d_in[4];
  const int*   idx   = (const int*)  d_in[5];
  const int*   esrc  = (const int*)  d_in[6];
  const float* W1  = (const float*)d_in[8];
  const float* b1  = (const float*)d_in[9];
  const float* W2  = (const float*)d_in[10];
  const float* b2  = (const float*)d_in[11];
  const float* g2  = (const float*)d_in[12];
  const float* be2 = (const float*)d_in[13];
  const float* W3  = (const float*)d_in[14];
  const float* b3  = (const float*)d_in[15];
  const float* g3  = (const float*)d_in[16];
  const float* be3 = (const float*)d_in[17];
  const float* expW  = (const float*)d_in[24];
  const float* expb  = (const float*)d_in[25];
  const float* expg  = (const float*)d_in[26];
  const float* expbe = (const float*)d_in[27];
  const float* dww  = (const float*)d_in[28];
  const float* dwg  = (const float*)d_in[30];
  const float* dwbe = (const float*)d_in[31];
  const float* pwW  = (const float*)d_in[32];
  const float* pwb  = (const float*)d_in[33];
  const float* pwg  = (const float*)d_in[34];
  const float* pwbe = (const float*)d_in[35];
  const float* cg   = (const float*)d_in[36];
  const float* cbe  = (const float*)d_in[37];
  const float* projW  = (const float*)d_in[38];
  const float* projb  = (const float*)d_in[39];
  const float* projg  = (const float*)d_in[40];
  const float* projbe = (const float*)d_in[41];
  float* out = (float*)d_out;

  const float fNE = (float)NE, fNM = (float)NM;

  prep_weights<<<2624, 256, 0, stream>>>(W1, W2, W3, expW, pwW, projW);
  prep_pos_x<<<(NP + 255)/256, 256, 0, stream>>>(pos, batch, refl, sf, x);
  tail_out<<<(NM + 255)/256, 256, 0, stream>>>(pos, batch, refl, sf, idx, out);
  zero_stats<<<1, 512, 0, stream>>>();

  k1_edge<<<K1_BLOCKS, 256, 0, stream>>>(esrc, idx, b1, b2);          // stats(pre2)
  param_bn<<<1, 512, 0, stream>>>(g2, be2, fNE, 64);
  scale_fold<0><<<32, 256, 0, stream>>>(b3, 128, 64);                 // fold bn2 into W3/b3
  k2_edge<<<K2_BLOCKS, 256, 0, stream>>>();                           // stats(pre3) + max/min
  param_bn<<<1, 512, 0, stream>>>(g3, be3, fNE, 128);
  k3_agg<<<NM*128/1024, 256, 0, stream>>>();

  // t1 = agg @ expW + expb
  gemm_mfma<1, 3, 2, false, false, true, false><<<dim3(469, 4), 256, 0, stream>>>(expb, NM, 512, 128);
  param_bn<<<1, 512, 0, stream>>>(expg, expbe, fNM, 512);
  ew_stats<2, 2><<<512, 256, 0, stream>>>(NM);                        // e = relu(bn(t1))
  param_dw<<<1, 512, 0, stream>>>(dww, dwg, dwbe, fNM, 512);
  // p0 = relu(bn_dw0(e)) @ pw0 + pwb0
  gemm_mfma<2, 4, 3, true, true, true, false><<<dim3(469, 4), 256, 0, stream>>>(pwb, NM, 512, 512);
  param_bn<<<1, 512, 0, stream>>>(pwg, pwbe, fNM, 512);
  ew_stats<3, 3><<<512, 256, 0, stream>>>(NM);                        // v0
  param_bn<<<1, 512, 0, stream>>>(cg, cbe, fNM, 512);
  ew_stats<3, 3><<<512, 256, 0, stream>>>(NM);                        // cmid
  param_dw<<<1, 512, 0, stream>>>(dww + 512, dwg + 512, dwbe + 512, fNM, 512);
  // p1
  gemm_mfma<3, 5, 2, true, true, true, false><<<dim3(469, 4), 256, 0, stream>>>(pwb + 512, NM, 512, 512);
  param_bn<<<1, 512, 0, stream>>>(pwg + 512, pwbe + 512, fNM, 512);
  ew_stats<2, 2><<<512, 256, 0, stream>>>(NM);                        // v1
  param_bn<<<1, 512, 0, stream>>>(cg + 512, cbe + 512, fNM, 512);
  scale_fold<1><<<32, 256, 0, stream>>>(projb, 128, 512);             // fold c1-bn into projW/projb
  // o = v1 @ projW' + pbadj  (f32 out, no prologue)
  gemm_mfma<2, 6, 0, false, false, false, true><<<dim3(469, 1), 256, 0, stream>>>(projb, NM, 128, 512);
  param_bn<<<1, 512, 0, stream>>>(projg, projbe, fNM, 128);
  final_out<<<NM*128/1024, 256, 0, stream>>>(out);
}

// Round 5
// 804.846 us; speedup vs baseline: 3.6828x; 1.0091x over previous
//
#include <hip/hip_runtime.h>
#include <hip/hip_bf16.h>
#include <cstdint>

#define DEV_INLINE __device__ __forceinline__

typedef unsigned short u16;
typedef unsigned int   u32;
typedef short bf16x8 __attribute__((ext_vector_type(8)));
typedef float f32x4  __attribute__((ext_vector_type(4)));

constexpr int NP = 120000, NB = 8, NM = 60000, KNN = 16;
constexpr int NE = NM * KNN;          // 960000
constexpr float EPS = 1e-5f;

constexpr size_t O_POS   = (size_t)NM * 128;
constexpr size_t O_BATCH = O_POS + (size_t)NM * 3;
constexpr size_t O_REFL  = O_BATCH + NM;
constexpr size_t O_SF    = O_REFL + NM;

// ---------------- device-global buffers -------------------------------------
__device__ float  g_pos_s[(size_t)NP * 4];
__device__ u16    g_xbf[(size_t)NP * 32];         // x in bf16
// pre2 in MFMA fragment-tile layout: tile t (16 rows=edges of center t):
// g_pre2[t*1024 + ks*512 + lane*8 + j] = pre2[t*16+(lane&15)][ks*32+(lane>>4)*8+j]
__device__ u16    g_pre2[(size_t)NE * 64];
__device__ u32    g_mm[(size_t)NM * 128];         // packed bf16 {lo=max, hi=min}
__device__ float  g_agg[(size_t)NM * 128];        // f32 residual
__device__ u16    g_aggbf[(size_t)NM * 128];      // bf16 GEMM input
__device__ u16    g_bufA[(size_t)NM * 512];
__device__ u16    g_bufB[(size_t)NM * 512];
__device__ float  g_obuf[(size_t)NM * 128];
__device__ float  g_sum[512], g_sqs[512], g_cfa[512], g_cfb[512];
__device__ float  g_b3adj[128], g_pbadj[128];
// transposed bf16 weights [N][K]
__device__ u16 g_w1t[64 * 64];      // K padded 36->64 (zeros)
__device__ u16 g_w2t[64 * 64];
__device__ u16 g_w3t[128 * 64];     // gets bn2-folded in place per launch
__device__ u16 g_expwt[512 * 128];
__device__ u16 g_pw0t[512 * 512];
__device__ u16 g_pw1t[512 * 512];
__device__ u16 g_projwt[128 * 512]; // gets c1-bn-folded in place per launch

template<int ID> DEV_INLINE const u16* ubufsel() {
  if constexpr (ID == 1) return g_aggbf;
  else if constexpr (ID == 2) return g_bufA;
  else return g_bufB;
}
template<int ID> DEV_INLINE u16* obufsel() {
  if constexpr (ID == 2) return g_bufA;
  else return g_bufB;
}
template<int ID> DEV_INLINE const u16* wsel() {
  if constexpr (ID == 3) return g_expwt;
  else if constexpr (ID == 4) return g_pw0t;
  else if constexpr (ID == 5) return g_pw1t;
  else return g_projwt;
}

// ---------------- helpers ----------------------------------------------------
DEV_INLINE float bf2f(u16 u) { u32 x = (u32)u << 16; float f; __builtin_memcpy(&f, &x, 4); return f; }
DEV_INLINE u16 f2bf(float f) {
  u32 x; __builtin_memcpy(&x, &f, 4);
  return (u16)((x + 0x7FFFu + ((x >> 16) & 1u)) >> 16);
}
DEV_INLINE u32 pack2(float a, float b) { return (u32)f2bf(a) | ((u32)f2bf(b) << 16); }

// affine (+optional relu) on 8 packed bf16 with register cf values
DEV_INLINE uint4 affine8r(uint4 v, float4 A0, float4 A1, float4 B0, float4 B1, bool relu) {
  float av[8] = {A0.x,A0.y,A0.z,A0.w,A1.x,A1.y,A1.z,A1.w};
  float bv[8] = {B0.x,B0.y,B0.z,B0.w,B1.x,B1.y,B1.z,B1.w};
  u32 u[4] = {v.x, v.y, v.z, v.w}, r[4];
#pragma unroll
  for (int q = 0; q < 4; q++) {
    float lo = bf2f((u16)(u[q] & 0xFFFFu));
    float hi = bf2f((u16)(u[q] >> 16));
    lo = fmaf(av[2*q],   lo, bv[2*q]);
    hi = fmaf(av[2*q+1], hi, bv[2*q+1]);
    if (relu) { lo = fmaxf(lo, 0.f); hi = fmaxf(hi, 0.f); }
    r[q] = (u32)f2bf(lo) | ((u32)f2bf(hi) << 16);
  }
  return make_uint4(r[0], r[1], r[2], r[3]);
}

// affine via global cf (k1/k2 path helper retained)
DEV_INLINE uint4 affine8(uint4 v, int kbase, bool relu) {
  u32 u[4] = {v.x, v.y, v.z, v.w};
  u32 r[4];
#pragma unroll
  for (int q = 0; q < 4; q++) {
    float lo = bf2f((u16)(u[q] & 0xFFFFu));
    float hi = bf2f((u16)(u[q] >> 16));
    lo = fmaf(g_cfa[kbase + 2*q],     lo, g_cfb[kbase + 2*q]);
    hi = fmaf(g_cfa[kbase + 2*q + 1], hi, g_cfb[kbase + 2*q + 1]);
    if (relu) { lo = fmaxf(lo, 0.f); hi = fmaxf(hi, 0.f); }
    r[q] = (u32)f2bf(lo) | ((u32)f2bf(hi) << 16);
  }
  return make_uint4(r[0], r[1], r[2], r[3]);
}

// ---------------- tiny kernels ----------------------------------------------
__global__ void prep_pos_x(const float* __restrict__ pos, const int* __restrict__ batch,
                           const float* __restrict__ refl, const float* __restrict__ sf,
                           const float* __restrict__ x) {
  int i = blockIdx.x * blockDim.x + threadIdx.x;
  if (i >= NP) return;
  float s = sf[batch[i]];
  float4 v;
  v.x = pos[(size_t)i*3+0] / s;
  v.y = pos[(size_t)i*3+1] / s;
  v.z = pos[(size_t)i*3+2] / s;
  v.w = refl[i];   // gate == 1 exactly
  *reinterpret_cast<float4*>(g_pos_s + (size_t)i*4) = v;
  const float4* xr = reinterpret_cast<const float4*>(x + (size_t)i*32);
#pragma unroll
  for (int q = 0; q < 4; q++) {
    float4 a = xr[q*2], b = xr[q*2+1];
    uint4 u = make_uint4(pack2(a.x,a.y), pack2(a.z,a.w), pack2(b.x,b.y), pack2(b.z,b.w));
    *reinterpret_cast<uint4*>(g_xbf + (size_t)i*32 + q*8) = u;
  }
}

__global__ void tail_out(const float* __restrict__ pos, const int* __restrict__ batch,
                         const float* __restrict__ refl, const float* __restrict__ sf,
                         const int* __restrict__ idx, float* __restrict__ out) {
  int i = blockIdx.x * blockDim.x + threadIdx.x;
  if (i < NM) {
    int p = idx[i];
    out[O_POS + (size_t)i*3+0] = pos[(size_t)p*3+0];
    out[O_POS + (size_t)i*3+1] = pos[(size_t)p*3+1];
    out[O_POS + (size_t)i*3+2] = pos[(size_t)p*3+2];
    out[O_BATCH + i] = (float)batch[p];
    out[O_REFL  + i] = refl[p];
  }
  if (i < NB) out[O_SF + i] = sf[i];
}

__global__ void zero_stats() {
  int t = threadIdx.x;
  g_sum[t] = 0.f; g_sqs[t] = 0.f;
}

// transpose + bf16-convert all weights (one kernel)
__global__ void prep_weights(const float* __restrict__ W1, const float* __restrict__ W2,
                             const float* __restrict__ W3, const float* __restrict__ expW,
                             const float* __restrict__ pwW, const float* __restrict__ projW) {
  int i = blockIdx.x * 256 + threadIdx.x;
  const int s0 = 4096, s1 = 4096, s2 = 8192, s3 = 65536, s4 = 262144, s5 = 262144, s6 = 65536;
  if (i < s0) { int n = i >> 6, k = i & 63; g_w1t[i] = (k < 36) ? f2bf(W1[k*64 + n]) : (u16)0; return; }
  i -= s0;
  if (i < s1) { int n = i >> 6, k = i & 63; g_w2t[i] = f2bf(W2[k*64 + n]); return; }
  i -= s1;
  if (i < s2) { int n = i >> 6, k = i & 63; g_w3t[i] = f2bf(W3[k*128 + n]); return; }
  i -= s2;
  if (i < s3) { int n = i >> 7, k = i & 127; g_expwt[i] = f2bf(expW[k*512 + n]); return; }
  i -= s3;
  if (i < s4) { int n = i >> 9, k = i & 511; g_pw0t[i] = f2bf(pwW[k*512 + n]); return; }
  i -= s4;
  if (i < s5) { int n = i >> 9, k = i & 511; g_pw1t[i] = f2bf(pwW[262144 + k*512 + n]); return; }
  i -= s5;
  if (i < s6) { int n = i >> 9, k = i & 511; g_projwt[i] = f2bf(projW[k*128 + n]); return; }
}

// param: BN of buffer whose stats are in g_sum/g_sqs; then zero stats for next user
__global__ void param_bn(const float* __restrict__ g, const float* __restrict__ be,
                         float n, int C) {
  int c = threadIdx.x;
  if (c < C) {
    float mean = g_sum[c] / n;
    float var  = fmaxf(g_sqs[c] / n - mean * mean, 0.f);
    float a = g[c] * rsqrtf(var + EPS);
    g_cfa[c] = a;
    g_cfb[c] = be[c] - a * mean;
  }
  __syncthreads();
  g_sum[c] = 0.f; g_sqs[c] = 0.f;
}

// BN of u = w*h + b_dw given stats of h (b_dw cancels)
__global__ void param_dw(const float* __restrict__ w, const float* __restrict__ g,
                         const float* __restrict__ be, float n, int C) {
  int c = threadIdx.x;
  if (c < C) {
    float mean = g_sum[c] / n;
    float var  = fmaxf(g_sqs[c] / n - mean * mean, 0.f);
    float r = rsqrtf(w[c]*w[c]*var + EPS);
    float a = w[c] * r * g[c];
    g_cfa[c] = a;
    g_cfb[c] = be[c] - a * mean;
  }
  __syncthreads();
  g_sum[c] = 0.f; g_sqs[c] = 0.f;
}

// Fold current g_cfa/g_cfb into a [N][K] bf16 weight (in place) + bias:
// bn(A)@W == A@(diag(a)W) + (b@W);  badj[n] = bias[n] + sum_k b_k * W[k][n]
template<int SID>
__global__ void scale_fold(const float* __restrict__ bias_in, int N, int K) {
  u16* Wt = (SID == 0) ? g_w3t : g_projwt;
  float* badj = (SID == 0) ? g_b3adj : g_pbadj;
  int w = (blockIdx.x * blockDim.x + threadIdx.x) >> 6;
  int lane = threadIdx.x & 63;
  if (w >= N) return;
  float acc = 0.f;
  for (int k = lane; k < K; k += 64) {
    float wv = bf2f(Wt[(size_t)w*K + k]);
    acc = fmaf(g_cfb[k], wv, acc);
    Wt[(size_t)w*K + k] = f2bf(g_cfa[k] * wv);
  }
#pragma unroll
  for (int o = 32; o; o >>= 1) acc += __shfl_xor(acc, o, 64);
  if (lane == 0) badj[w] = bias_in[w] + acc;
}

// ---------------- K1: wave-autonomous gather + MLP1 + MLP2 ------------------
constexpr int K1_BLOCKS = 960;
__launch_bounds__(256)
__global__ void k1_edge(const int* __restrict__ esrc, const int* __restrict__ idx,
                        const float* __restrict__ b1v, const float* __restrict__ b2v) {
  __shared__ u16 sH[4][16][72];
  __shared__ float ssum[64], ssqs[64];
  const int tid = threadIdx.x;
  if (tid < 64) { ssum[tid] = 0.f; ssqs[tid] = 0.f; }
  __syncthreads();
  const int w = tid >> 6, lane = tid & 63, l15 = lane & 15, l4 = lane >> 4;
  u16 (*sh)[72] = sH[w];
  bf16x8 w1f[2][4], w2f[2][4];
#pragma unroll
  for (int ks = 0; ks < 2; ks++)
#pragma unroll
    for (int fc = 0; fc < 4; fc++) {
      w1f[ks][fc] = *reinterpret_cast<const bf16x8*>(g_w1t + (size_t)(fc*16+l15)*64 + ks*32 + l4*8);
      w2f[ks][fc] = *reinterpret_cast<const bf16x8*>(g_w2t + (size_t)(fc*16+l15)*64 + ks*32 + l4*8);
    }
  float b1r[4], b2r[4];
#pragma unroll
  for (int fc = 0; fc < 4; fc++) { b1r[fc] = b1v[fc*16+l15]; b2r[fc] = b2v[fc*16+l15]; }
  float s8[4] = {}, q8[4] = {};
  const int t0 = blockIdx.x * 4 + w;
  const int TSTRIDE = K1_BLOCKS * 4;
  int   s_cur = esrc[t0*16 + l15];
  uint4 x_cur = *reinterpret_cast<const uint4*>(g_xbf + (size_t)s_cur*32 + l4*8);
  float4 ps_cur = make_float4(0.f,0.f,0.f,0.f);
  if (l4 == 0) ps_cur = *reinterpret_cast<const float4*>(g_pos_s + (size_t)s_cur*4);
  float4 pc_cur = *reinterpret_cast<const float4*>(g_pos_s + (size_t)idx[t0]*4);

  for (int t = t0; t < NM; t += TSTRIDE) {
    const int tn = t + TSTRIDE;
    int s_nx = 0; uint4 x_nx = make_uint4(0,0,0,0);
    float4 ps_nx = ps_cur, pc_nx = pc_cur;
    if (tn < NM) {
      s_nx = esrc[tn*16 + l15];
      x_nx = *reinterpret_cast<const uint4*>(g_xbf + (size_t)s_nx*32 + l4*8);
      if (l4 == 0) ps_nx = *reinterpret_cast<const float4*>(g_pos_s + (size_t)s_nx*4);
      pc_nx = *reinterpret_cast<const float4*>(g_pos_s + (size_t)idx[tn]*4);
    }
    bf16x8 a0 = __builtin_bit_cast(bf16x8, x_cur);
    uint4 r4 = make_uint4(0,0,0,0);
    if (l4 == 0) {
      r4.x = pack2(ps_cur.x - pc_cur.x, ps_cur.y - pc_cur.y);
      r4.y = pack2(ps_cur.z - pc_cur.z, ps_cur.w - pc_cur.w);
    }
    bf16x8 a1 = __builtin_bit_cast(bf16x8, r4);
    f32x4 acc1[4] = {};
#pragma unroll
    for (int fc = 0; fc < 4; fc++) {
      acc1[fc] = __builtin_amdgcn_mfma_f32_16x16x32_bf16(a0, w1f[0][fc], acc1[fc], 0, 0, 0);
      acc1[fc] = __builtin_amdgcn_mfma_f32_16x16x32_bf16(a1, w1f[1][fc], acc1[fc], 0, 0, 0);
    }
#pragma unroll
    for (int fc = 0; fc < 4; fc++)
#pragma unroll
      for (int r = 0; r < 4; r++)
        sh[l4*4 + r][fc*16 + l15] = f2bf(fmaxf(acc1[fc][r] + b1r[fc], 0.f));
    bf16x8 h0  = *reinterpret_cast<const bf16x8*>(&sh[l15][l4*8]);
    bf16x8 h1v = *reinterpret_cast<const bf16x8*>(&sh[l15][32 + l4*8]);
    f32x4 acc2[4] = {};
#pragma unroll
    for (int fc = 0; fc < 4; fc++) {
      acc2[fc] = __builtin_amdgcn_mfma_f32_16x16x32_bf16(h0,  w2f[0][fc], acc2[fc], 0, 0, 0);
      acc2[fc] = __builtin_amdgcn_mfma_f32_16x16x32_bf16(h1v, w2f[1][fc], acc2[fc], 0, 0, 0);
    }
#pragma unroll
    for (int fc = 0; fc < 4; fc++)
#pragma unroll
      for (int r = 0; r < 4; r++) {
        float v = fmaxf(acc2[fc][r] + b2r[fc], 0.f);
        s8[fc] += v; q8[fc] += v*v;
        sh[l4*4 + r][fc*16 + l15] = f2bf(v);
      }
    uint4 p0 = *reinterpret_cast<const uint4*>(&sh[l15][l4*8]);
    uint4 p1 = *reinterpret_cast<const uint4*>(&sh[l15][32 + l4*8]);
    *reinterpret_cast<uint4*>(g_pre2 + (size_t)t*1024 + lane*8)       = p0;
    *reinterpret_cast<uint4*>(g_pre2 + (size_t)t*1024 + 512 + lane*8) = p1;
    s_cur = s_nx; x_cur = x_nx; ps_cur = ps_nx; pc_cur = pc_nx;
  }
#pragma unroll
  for (int fc = 0; fc < 4; fc++) {
    float sv = s8[fc], qv = q8[fc];
    sv += __shfl_xor(sv, 16, 64); sv += __shfl_xor(sv, 32, 64);
    qv += __shfl_xor(qv, 16, 64); qv += __shfl_xor(qv, 32, 64);
    if (l4 == 0) { atomicAdd(&ssum[fc*16 + l15], sv); atomicAdd(&ssqs[fc*16 + l15], qv); }
  }
  __syncthreads();
  if (tid < 64) { atomicAdd(&g_sum[tid], ssum[tid]); atomicAdd(&g_sqs[tid], ssqs[tid]); }
}

// ---------------- K2: LDS-free MLP3 + stats + per-center max/min ------------
constexpr int K2_BLOCKS = 960;
__launch_bounds__(256)
__global__ void k2_edge() {
  __shared__ float ssum[128], ssqs[128];
  const int tid = threadIdx.x;
  if (tid < 128) { ssum[tid] = 0.f; ssqs[tid] = 0.f; }
  __syncthreads();
  const int lane = tid & 63, l15 = lane & 15, l4 = lane >> 4;
  const int wglobal = blockIdx.x * 4 + (tid >> 6);
  const int WSTRIDE = K2_BLOCKS * 4;
  bf16x8 w3f[2][8];
#pragma unroll
  for (int ks = 0; ks < 2; ks++)
#pragma unroll
    for (int fc = 0; fc < 8; fc++)
      w3f[ks][fc] = *reinterpret_cast<const bf16x8*>(g_w3t + (size_t)(fc*16 + l15)*64 + ks*32 + l4*8);
  float bv[8];
#pragma unroll
  for (int fc = 0; fc < 8; fc++) bv[fc] = g_b3adj[fc*16 + l15];
  float s[8] = {}, q[8] = {};
  int t = wglobal;
  uint4 an0 = make_uint4(0,0,0,0), an1 = an0;
  if (t < NM) {
    const uint4* p = reinterpret_cast<const uint4*>(g_pre2 + (size_t)t*1024 + lane*8);
    an0 = p[0]; an1 = p[64];
  }
  for (; t < NM; t += WSTRIDE) {
    uint4 a0 = an0, a1 = an1;
    int tn = t + WSTRIDE;
    if (tn < NM) {
      const uint4* p = reinterpret_cast<const uint4*>(g_pre2 + (size_t)tn*1024 + lane*8);
      an0 = p[0]; an1 = p[64];
    }
    bf16x8 af0 = __builtin_bit_cast(bf16x8, a0);
    bf16x8 af1 = __builtin_bit_cast(bf16x8, a1);
    f32x4 acc[8] = {};
#pragma unroll
    for (int fc = 0; fc < 8; fc++) {
      acc[fc] = __builtin_amdgcn_mfma_f32_16x16x32_bf16(af0, w3f[0][fc], acc[fc], 0, 0, 0);
      acc[fc] = __builtin_amdgcn_mfma_f32_16x16x32_bf16(af1, w3f[1][fc], acc[fc], 0, 0, 0);
    }
    u32 rbase = (u32)t * 128u;
#pragma unroll
    for (int fc = 0; fc < 8; fc++) {
      float v0 = fmaxf(acc[fc][0] + bv[fc], 0.f);
      float v1 = fmaxf(acc[fc][1] + bv[fc], 0.f);
      float v2 = fmaxf(acc[fc][2] + bv[fc], 0.f);
      float v3 = fmaxf(acc[fc][3] + bv[fc], 0.f);
      s[fc] += (v0 + v1) + (v2 + v3);
      q[fc] += (v0*v0 + v1*v1) + (v2*v2 + v3*v3);
      float mx = fmaxf(fmaxf(v0, v1), fmaxf(v2, v3));
      float mn = fminf(fminf(v0, v1), fminf(v2, v3));
      mx = fmaxf(mx, __shfl_xor(mx, 16, 64)); mx = fmaxf(mx, __shfl_xor(mx, 32, 64));
      mn = fminf(mn, __shfl_xor(mn, 16, 64)); mn = fminf(mn, __shfl_xor(mn, 32, 64));
      if (l4 == (fc & 3))
        g_mm[rbase + fc*16 + l15] = (u32)f2bf(mx) | ((u32)f2bf(mn) << 16);
    }
  }
#pragma unroll
  for (int fc = 0; fc < 8; fc++) {
    float sv = s[fc], qv = q[fc];
    sv += __shfl_xor(sv, 16, 64); sv += __shfl_xor(sv, 32, 64);
    qv += __shfl_xor(qv, 16, 64); qv += __shfl_xor(qv, 32, 64);
    if (l4 == 0) { atomicAdd(&ssum[fc*16 + l15], sv); atomicAdd(&ssqs[fc*16 + l15], qv); }
  }
  __syncthreads();
  if (tid < 128) { atomicAdd(&g_sum[tid], ssum[tid]); atomicAdd(&g_sqs[tid], ssqs[tid]); }
}

// K3: agg = bn3-affine of packed max/min (sign-select); write f32 residual + bf16
__global__ void k3_agg() {
  int i4 = (blockIdx.x * 256 + threadIdx.x) * 4;
  if (i4 >= NM * 128) return;
  int c = i4 & 127;
  uint4 mm = *reinterpret_cast<const uint4*>(g_mm + i4);
  float4 a = *reinterpret_cast<const float4*>(g_cfa + c);
  float4 b = *reinterpret_cast<const float4*>(g_cfb + c);
  u32 u[4] = {mm.x, mm.y, mm.z, mm.w};
  float av[4] = {a.x, a.y, a.z, a.w};
  float bb[4] = {b.x, b.y, b.z, b.w};
  float4 r;
  float* rr = &r.x;
#pragma unroll
  for (int j = 0; j < 4; j++) {
    float mx = bf2f((u16)(u[j] & 0xFFFFu));
    float mn = bf2f((u16)(u[j] >> 16));
    rr[j] = av[j] > 0.f ? fmaf(av[j], mx, bb[j]) : fmaf(av[j], mn, bb[j]);
  }
  *reinterpret_cast<float4*>(g_agg + i4) = r;
  uint2 pk; pk.x = pack2(r.x, r.y); pk.y = pack2(r.z, r.w);
  *reinterpret_cast<uint2*>(g_aggbf + i4) = pk;
}

// ---------------- MFMA GEMM: Out[M,N] = PRO(A[M,K]) @ Bt[N,K]^T + bias ------
// 128x128 tile, 256 thr (4 waves 2x2), BK=32, DOUBLE-BUFFERED LDS,
// one barrier per K-step, next-tile loads issued before MFMA (T3-min pipeline).
template<int AID, int WID, int OID, bool PRO_AFF, bool PRO_RELU, bool OUT_BF16, bool BIAS_DEV>
__launch_bounds__(256, 3)
__global__ void gemm_mfma(const float* __restrict__ bias, int Mrows, int Ncols, int Kdim) {
  const u16* __restrict__ A  = ubufsel<AID>();
  const u16* __restrict__ Bt = wsel<WID>();
  __shared__ u16 As[2][128][40];
  __shared__ u16 Bs[2][128][40];
  __shared__ float ssum[128], ssqs[128];
  const int tid = threadIdx.x;
  const int m0 = blockIdx.x * 128, n0 = blockIdx.y * 128;
  if (tid < 128) { ssum[tid] = 0.f; ssqs[tid] = 0.f; }
  const int wave = tid >> 6, lane = tid & 63, l15 = lane & 15, l4 = lane >> 4;
  const int wr = wave >> 1, wc = wave & 1;
  const int srow = tid >> 1, sseg = tid & 1;      // staged row, 16-elem K-segment
  const int gr = m0 + srow;
  const bool aval = gr < Mrows;
  const size_t aoff = (size_t)gr * Kdim + sseg * 16;
  const size_t boff = (size_t)(n0 + srow) * Kdim + sseg * 16;
  f32x4 acc[4][4] = {};
  const int nt = Kdim >> 5;

  uint4 va0, va1, vb0, vb1;
  float4 ca0, ca1, ca2, ca3, cb0, cb1, cb2, cb3;

  auto LOAD = [&](int t) {
    const int k0 = t * 32;
    va0 = make_uint4(0,0,0,0); va1 = va0;
    if (aval) {
      const uint4* p = reinterpret_cast<const uint4*>(A + aoff + k0);
      va0 = p[0]; va1 = p[1];
    }
    const uint4* pb = reinterpret_cast<const uint4*>(Bt + boff + k0);
    vb0 = pb[0]; vb1 = pb[1];
    if (PRO_AFF) {
      const int kb = k0 + sseg * 16;
      ca0 = *reinterpret_cast<const float4*>(g_cfa + kb);
      ca1 = *reinterpret_cast<const float4*>(g_cfa + kb + 4);
      ca2 = *reinterpret_cast<const float4*>(g_cfa + kb + 8);
      ca3 = *reinterpret_cast<const float4*>(g_cfa + kb + 12);
      cb0 = *reinterpret_cast<const float4*>(g_cfb + kb);
      cb1 = *reinterpret_cast<const float4*>(g_cfb + kb + 4);
      cb2 = *reinterpret_cast<const float4*>(g_cfb + kb + 8);
      cb3 = *reinterpret_cast<const float4*>(g_cfb + kb + 12);
    }
  };
  auto WRITE = [&](int buf) {
    uint4 wa0 = va0, wa1 = va1;
    if (PRO_AFF) {
      wa0 = affine8r(va0, ca0, ca1, cb0, cb1, PRO_RELU);
      wa1 = affine8r(va1, ca2, ca3, cb2, cb3, PRO_RELU);
    }
    *reinterpret_cast<uint4*>(&As[buf][srow][sseg*16])     = wa0;
    *reinterpret_cast<uint4*>(&As[buf][srow][sseg*16 + 8]) = wa1;
    *reinterpret_cast<uint4*>(&Bs[buf][srow][sseg*16])     = vb0;
    *reinterpret_cast<uint4*>(&Bs[buf][srow][sseg*16 + 8]) = vb1;
  };
  auto MFMA = [&](int buf) {
    bf16x8 af[4], bf[4];
#pragma unroll
    for (int fr = 0; fr < 4; fr++)
      af[fr] = *reinterpret_cast<const bf16x8*>(&As[buf][wr*64 + fr*16 + l15][l4*8]);
#pragma unroll
    for (int fc = 0; fc < 4; fc++)
      bf[fc] = *reinterpret_cast<const bf16x8*>(&Bs[buf][wc*64 + fc*16 + l15][l4*8]);
#pragma unroll
    for (int fr = 0; fr < 4; fr++)
#pragma unroll
      for (int fc = 0; fc < 4; fc++)
        acc[fr][fc] = __builtin_amdgcn_mfma_f32_16x16x32_bf16(af[fr], bf[fc], acc[fr][fc], 0, 0, 0);
  };

  LOAD(0);
  WRITE(0);
  __syncthreads();
  int cur = 0;
  for (int t = 0; ; ) {
    const bool more = (t + 1 < nt);
    if (more) LOAD(t + 1);     // issue next-tile loads; latency hides under MFMA
    MFMA(cur);
    if (!more) break;
    WRITE(cur ^ 1);            // vmcnt wait happens here, after MFMA covered it
    __syncthreads();           // single barrier per K-step (see race analysis)
    cur ^= 1; ++t;
  }

  // epilogue: bias + stats + store
  const int orow = m0 + wr*64 + l4*4;
#pragma unroll
  for (int fc = 0; fc < 4; fc++) {
    int col = n0 + wc*64 + fc*16 + l15;
    float bvv = BIAS_DEV ? g_pbadj[col] : bias[col];
    float s = 0.f, q = 0.f;
#pragma unroll
    for (int fr = 0; fr < 4; fr++)
#pragma unroll
      for (int r = 0; r < 4; r++) {
        int row = orow + fr*16 + r;
        if (row < Mrows) {
          float v = acc[fr][fc][r] + bvv;
          s += v; q += v*v;
          if (OUT_BF16) obufsel<OID>()[(size_t)row*Ncols + col] = f2bf(v);
          else          g_obuf[(size_t)row*Ncols + col] = v;
        }
      }
    atomicAdd(&ssum[wc*64 + fc*16 + l15], s);
    atomicAdd(&ssqs[wc*64 + fc*16 + l15], q);
  }
  __syncthreads();
  if (tid < 128) { atomicAdd(&g_sum[n0 + tid], ssum[tid]); atomicAdd(&g_sqs[n0 + tid], ssqs[tid]); }
}

// ---------------- EW: y = relu(a*x+b) (bf16->bf16) + fused stats -------------
template<int INID, int OUTID>
__launch_bounds__(256)
__global__ void ew_stats(int rows) {
  const u16* __restrict__ X = ubufsel<INID>();
  u16* __restrict__ Y = obufsel<OUTID>();
  __shared__ float ssum[512], ssqs[512];
  const int tid = threadIdx.x;
  ssum[tid] = 0.f; ssum[tid+256] = 0.f; ssqs[tid] = 0.f; ssqs[tid+256] = 0.f;
  __syncthreads();
  const int c0 = (tid & 63) * 8;
  const int rl = tid >> 6;
  float a[8], b[8];
#pragma unroll
  for (int j = 0; j < 8; j++) { a[j] = g_cfa[c0+j]; b[j] = g_cfb[c0+j]; }
  float s[8] = {}, q[8] = {};
  for (int r = blockIdx.x*4 + rl; r < rows; r += gridDim.x*4) {
    uint4 v = *reinterpret_cast<const uint4*>(X + (size_t)r*512 + c0);
    u32 u[4] = {v.x, v.y, v.z, v.w}, o[4];
#pragma unroll
    for (int t = 0; t < 4; t++) {
      float lo = bf2f((u16)(u[t] & 0xFFFFu));
      float hi = bf2f((u16)(u[t] >> 16));
      lo = fmaxf(fmaf(a[2*t],   lo, b[2*t]),   0.f);
      hi = fmaxf(fmaf(a[2*t+1], hi, b[2*t+1]), 0.f);
      s[2*t] += lo; q[2*t] += lo*lo; s[2*t+1] += hi; q[2*t+1] += hi*hi;
      o[t] = (u32)f2bf(lo) | ((u32)f2bf(hi) << 16);
    }
    *reinterpret_cast<uint4*>(Y + (size_t)r*512 + c0) = make_uint4(o[0], o[1], o[2], o[3]);
  }
#pragma unroll
  for (int j = 0; j < 8; j++) { atomicAdd(&ssum[c0+j], s[j]); atomicAdd(&ssqs[c0+j], q[j]); }
  __syncthreads();
  atomicAdd(&g_sum[tid],     ssum[tid]);     atomicAdd(&g_sqs[tid],     ssqs[tid]);
  atomicAdd(&g_sum[tid+256], ssum[tid+256]); atomicAdd(&g_sqs[tid+256], ssqs[tid+256]);
}

__global__ void final_out(float* __restrict__ out) {
  int i4 = (blockIdx.x * 256 + threadIdx.x) * 4;
  if (i4 >= NM * 128) return;
  int c = i4 & 127;
  float4 o  = *reinterpret_cast<const float4*>(g_obuf + i4);
  float4 ag = *reinterpret_cast<const float4*>(g_agg + i4);
  float4 a  = *reinterpret_cast<const float4*>(g_cfa + c);
  float4 b  = *reinterpret_cast<const float4*>(g_cfb + c);
  float4 r;
  r.x = fmaxf(fmaf(a.x, o.x, b.x) + ag.x, 0.f);
  r.y = fmaxf(fmaf(a.y, o.y, b.y) + ag.y, 0.f);
  r.z = fmaxf(fmaf(a.z, o.z, b.z) + ag.z, 0.f);
  r.w = fmaxf(fmaf(a.w, o.w, b.w) + ag.w, 0.f);
  *reinterpret_cast<float4*>(out + i4) = r;
}

// ---------------- host launch ------------------------------------------------
extern "C" void kernel_launch(void* const* d_in, const int* in_sizes, int n_in,
                              void* d_out, int out_size, void* d_ws, size_t ws_size,
                              hipStream_t stream) {
  const float* x     = (const float*)d_in[0];
  const float* pos   = (const float*)d_in[1];
  const int*   batch = (const int*)  d_in[2];
  const float* refl  = (const float*)d_in[3];
  const float* sf    = (const float*)d_in[4];
  const int*   idx   = (const int*)  d_in[5];
  const int*   esrc  = (const int*)  d_in[6];
  const float* W1  = (const float*)d_in[8];
  const float* b1  = (const float*)d_in[9];
  const float* W2  = (const float*)d_in[10];
  const float* b2  = (const float*)d_in[11];
  const float* g2  = (const float*)d_in[12];
  const float* be2 = (const float*)d_in[13];
  const float* W3  = (const float*)d_in[14];
  const float* b3  = (const float*)d_in[15];
  const float* g3  = (const float*)d_in[16];
  const float* be3 = (const float*)d_in[17];
  const float* expW  = (const float*)d_in[24];
  const float* expb  = (const float*)d_in[25];
  const float* expg  = (const float*)d_in[26];
  const float* expbe = (const float*)d_in[27];
  const float* dww  = (const float*)d_in[28];
  const float* dwg  = (const float*)d_in[30];
  const float* dwbe = (const float*)d_in[31];
  const float* pwW  = (const float*)d_in[32];
  const float* pwb  = (const float*)d_in[33];
  const float* pwg  = (const float*)d_in[34];
  const float* pwbe = (const float*)d_in[35];
  const float* cg   = (const float*)d_in[36];
  const float* cbe  = (const float*)d_in[37];
  const float* projW  = (const float*)d_in[38];
  const float* projb  = (const float*)d_in[39];
  const float* projg  = (const float*)d_in[40];
  const float* projbe = (const float*)d_in[41];
  float* out = (float*)d_out;

  const float fNE = (float)NE, fNM = (float)NM;

  prep_weights<<<2624, 256, 0, stream>>>(W1, W2, W3, expW, pwW, projW);
  prep_pos_x<<<(NP + 255)/256, 256, 0, stream>>>(pos, batch, refl, sf, x);
  tail_out<<<(NM + 255)/256, 256, 0, stream>>>(pos, batch, refl, sf, idx, out);
  zero_stats<<<1, 512, 0, stream>>>();

  k1_edge<<<K1_BLOCKS, 256, 0, stream>>>(esrc, idx, b1, b2);          // stats(pre2)
  param_bn<<<1, 512, 0, stream>>>(g2, be2, fNE, 64);
  scale_fold<0><<<32, 256, 0, stream>>>(b3, 128, 64);                 // fold bn2 into W3/b3
  k2_edge<<<K2_BLOCKS, 256, 0, stream>>>();                           // stats(pre3) + max/min
  param_bn<<<1, 512, 0, stream>>>(g3, be3, fNE, 128);
  k3_agg<<<NM*128/1024, 256, 0, stream>>>();

  // t1 = agg @ expW + expb
  gemm_mfma<1, 3, 2, false, false, true, false><<<dim3(469, 4), 256, 0, stream>>>(expb, NM, 512, 128);
  param_bn<<<1, 512, 0, stream>>>(expg, expbe, fNM, 512);
  ew_stats<2, 2><<<512, 256, 0, stream>>>(NM);                        // e = relu(bn(t1))
  param_dw<<<1, 512, 0, stream>>>(dww, dwg, dwbe, fNM, 512);
  // p0 = relu(bn_dw0(e)) @ pw0 + pwb0
  gemm_mfma<2, 4, 3, true, true, true, false><<<dim3(469, 4), 256, 0, stream>>>(pwb, NM, 512, 512);
  param_bn<<<1, 512, 0, stream>>>(pwg, pwbe, fNM, 512);
  ew_stats<3, 3><<<512, 256, 0, stream>>>(NM);                        // v0
  param_bn<<<1, 512, 0, stream>>>(cg, cbe, fNM, 512);
  ew_stats<3, 3><<<512, 256, 0, stream>>>(NM);                        // cmid
  param_dw<<<1, 512, 0, stream>>>(dww + 512, dwg + 512, dwbe + 512, fNM, 512);
  // p1
  gemm_mfma<3, 5, 2, true, true, true, false><<<dim3(469, 4), 256, 0, stream>>>(pwb + 512, NM, 512, 512);
  param_bn<<<1, 512, 0, stream>>>(pwg + 512, pwbe + 512, fNM, 512);
  ew_stats<2, 2><<<512, 256, 0, stream>>>(NM);                        // v1
  param_bn<<<1, 512, 0, stream>>>(cg + 512, cbe + 512, fNM, 512);
  scale_fold<1><<<32, 256, 0, stream>>>(projb, 128, 512);             // fold c1-bn into projW/projb
  // o = v1 @ projW' + pbadj  (f32 out, no prologue)
  gemm_mfma<2, 6, 0, false, false, false, true><<<dim3(469, 1), 256, 0, stream>>>(projb, NM, 128, 512);
  param_bn<<<1, 512, 0, stream>>>(projg, projbe, fNM, 128);
  final_out<<<NM*128/1024, 256, 0, stream>>>(out);
}